// Round 1
// baseline (843.424 us; speedup 1.0000x reference)
//
#include <hip/hip_runtime.h>
#include <hip/hip_bf16.h>
#include <stdint.h>

// ---------------------------------------------------------------------------
// BitNet GQA block on MI355X.
// Pipeline: absmean(W) -> ternary-quant W (bf16 {-1,0,1})
//           row-absmax(x) -> int8-quant x (bf16 ints)
//           QKV GEMM (bf16 MFMA, integer-exact) -> RoPE/reshape
//           causal flash attention (bf16 MFMA) -> quant -> O-proj GEMM
// ---------------------------------------------------------------------------

typedef __bf16 bf16x8 __attribute__((ext_vector_type(8)));
typedef float f32x4 __attribute__((ext_vector_type(4)));
typedef unsigned short u16x8 __attribute__((ext_vector_type(8)));
typedef unsigned short u16x4 __attribute__((ext_vector_type(4)));

__device__ __forceinline__ unsigned short f2bf(float f) {
  union { float f; unsigned int u; } v; v.f = f;
  unsigned int r = v.u + 0x7fffu + ((v.u >> 16) & 1u);   // RNE
  return (unsigned short)(r >> 16);
}

__device__ __forceinline__ f32x4 mfma16(bf16x8 a, bf16x8 b, f32x4 c) {
  return __builtin_amdgcn_mfma_f32_16x16x32_bf16(a, b, c, 0, 0, 0);
}

// ---------------- abs-sum reduction (for absmean weight scale) --------------
__global__ void absum_k(const float* __restrict__ w, long n4, float* __restrict__ out) {
  long i = (long)blockIdx.x * blockDim.x + threadIdx.x;
  long stride = (long)gridDim.x * blockDim.x;
  const float4* w4 = (const float4*)w;
  float s = 0.f;
  for (; i < n4; i += stride) {
    float4 v = w4[i];
    s += fabsf(v.x) + fabsf(v.y) + fabsf(v.z) + fabsf(v.w);
  }
  #pragma unroll
  for (int o = 32; o; o >>= 1) s += __shfl_down(s, o);
  __shared__ float sm[4];
  int lane = threadIdx.x & 63, wv = threadIdx.x >> 6;
  if (lane == 0) sm[wv] = s;
  __syncthreads();
  if (threadIdx.x == 0) atomicAdd(out, sm[0] + sm[1] + sm[2] + sm[3]);
}

__global__ void finalize_k(const float* __restrict__ sums, float* __restrict__ sw) {
  int i = threadIdx.x;
  if (i < 4) {
    const float inv[4] = {1.f/(2048.f*2048.f), 1.f/(512.f*2048.f),
                          1.f/(512.f*2048.f), 1.f/(2048.f*2048.f)};
    sw[i] = sums[i] * inv[i] + 1e-5f;
  }
}

// ---------------- ternary weight quantization (store bf16 {-1,0,1}) ---------
__global__ void quantw_k(const float* __restrict__ w, unsigned short* __restrict__ o,
                         long n4, const float* __restrict__ swp) {
  float sw = *swp;
  long i = (long)blockIdx.x * blockDim.x + threadIdx.x;
  long stride = (long)gridDim.x * blockDim.x;
  const float4* w4 = (const float4*)w;
  u16x4* o4 = (u16x4*)o;
  for (; i < n4; i += stride) {
    float4 v = w4[i];
    u16x4 t;
    t[0] = f2bf(fminf(fmaxf(rintf(v.x / sw), -1.f), 1.f));
    t[1] = f2bf(fminf(fmaxf(rintf(v.y / sw), -1.f), 1.f));
    t[2] = f2bf(fminf(fmaxf(rintf(v.z / sw), -1.f), 1.f));
    t[3] = f2bf(fminf(fmaxf(rintf(v.w / sw), -1.f), 1.f));
    o4[i] = t;
  }
}

// ---------------- RoPE tables [2048][64] ------------------------------------
__global__ void ropetab_k(float* __restrict__ cosT, float* __restrict__ sinT) {
  int idx = blockIdx.x * 256 + threadIdx.x;   // 131072 total
  int s = idx >> 6, d = idx & 63;
  float freq = expf(-(float)d * (9.210340371976184f / 64.0f)); // theta^(-d/64)
  float ang = (float)s * freq;
  cosT[idx] = cosf(ang);
  sinT[idx] = sinf(ang);
}

// ---------------- activation quantization (per-row absmax, 8-bit) -----------
__global__ __launch_bounds__(256) void quanta_k(const float* __restrict__ x,
                                                unsigned short* __restrict__ xq,
                                                float* __restrict__ rs) {
  int row = blockIdx.x;
  const float* xr = x + (size_t)row * 2048;
  int tid = threadIdx.x;
  float4 v0 = ((const float4*)xr)[tid * 2];
  float4 v1 = ((const float4*)xr)[tid * 2 + 1];
  float m = fmaxf(fmaxf(fmaxf(fabsf(v0.x), fabsf(v0.y)), fmaxf(fabsf(v0.z), fabsf(v0.w))),
                  fmaxf(fmaxf(fabsf(v1.x), fabsf(v1.y)), fmaxf(fabsf(v1.z), fabsf(v1.w))));
  #pragma unroll
  for (int o = 32; o; o >>= 1) m = fmaxf(m, __shfl_xor(m, o));
  __shared__ float sm[4];
  if ((tid & 63) == 0) sm[tid >> 6] = m;
  __syncthreads();
  m = fmaxf(fmaxf(sm[0], sm[1]), fmaxf(sm[2], sm[3]));
  float rm = fmaxf(m, 1e-5f);
  float sx = 127.0f / rm;
  float vv[8] = {v0.x, v0.y, v0.z, v0.w, v1.x, v1.y, v1.z, v1.w};
  u16x8 o8;
  #pragma unroll
  for (int j = 0; j < 8; j++) {
    float r = rintf(vv[j] * sx);
    r = fminf(fmaxf(r, -128.f), 127.f);
    o8[j] = f2bf(r);               // small ints: exact in bf16
  }
  ((u16x8*)(xq + (size_t)row * 2048))[tid] = o8;
  if (tid == 0) rs[row] = rm * (1.0f / 127.0f);   // = 1/sx
}

// ---------------- GEMM: C[M][N] = scale * (A[M][K] . Bt[N][K]^T) ------------
// A, Bt bf16 (integer values); C fp32.  mode 0: QKV segments, mode 1: Wo.
__global__ __launch_bounds__(256) void gemm_k(const unsigned short* __restrict__ A,
                                              const unsigned short* __restrict__ Bt,
                                              float* __restrict__ C,
                                              int M, int N, int K,
                                              const float* __restrict__ rowscale,
                                              const float* __restrict__ sw, int mode) {
  __shared__ unsigned short As[128][40];   // +8 pad: 80B rows, 2-way banks
  __shared__ unsigned short Bs[128][40];
  int tid = threadIdx.x;
  int lane = tid & 63, wv = tid >> 6;
  int g = lane >> 4, li = lane & 15;
  int wm = wv >> 1, wn = wv & 1;
  int m0 = blockIdx.y * 128, n0 = blockIdx.x * 128;
  int lr = tid >> 2;            // staging row 0..63
  int lc = (tid & 3) * 8;       // staging col {0,8,16,24}

  f32x4 acc[4][4] = {};

  for (int k0 = 0; k0 < K; k0 += 32) {
    u16x8 a0 = *(const u16x8*)&A[(size_t)(m0 + lr) * K + k0 + lc];
    u16x8 a1 = *(const u16x8*)&A[(size_t)(m0 + 64 + lr) * K + k0 + lc];
    u16x8 b0 = *(const u16x8*)&Bt[(size_t)(n0 + lr) * K + k0 + lc];
    u16x8 b1 = *(const u16x8*)&Bt[(size_t)(n0 + 64 + lr) * K + k0 + lc];
    __syncthreads();     // previous iter's frag reads complete
    *(u16x8*)&As[lr][lc] = a0;
    *(u16x8*)&As[64 + lr][lc] = a1;
    *(u16x8*)&Bs[lr][lc] = b0;
    *(u16x8*)&Bs[64 + lr][lc] = b1;
    __syncthreads();
    bf16x8 af[4], bfr[4];
    #pragma unroll
    for (int i = 0; i < 4; i++) af[i]  = *(const bf16x8*)&As[wm * 64 + i * 16 + li][g * 8];
    #pragma unroll
    for (int j = 0; j < 4; j++) bfr[j] = *(const bf16x8*)&Bs[wn * 64 + j * 16 + li][g * 8];
    #pragma unroll
    for (int i = 0; i < 4; i++)
      #pragma unroll
      for (int j = 0; j < 4; j++)
        acc[i][j] = mfma16(af[i], bfr[j], acc[i][j]);
  }

  #pragma unroll
  for (int i = 0; i < 4; i++) {
    int row = m0 + wm * 64 + i * 16 + g * 4;
    #pragma unroll
    for (int j = 0; j < 4; j++) {
      int col = n0 + wn * 64 + j * 16 + li;
      float s = (mode == 0) ? ((col < 2048) ? sw[0] : (col < 2560 ? sw[1] : sw[2]))
                            : sw[3];
      #pragma unroll
      for (int r = 0; r < 4; r++)
        C[(size_t)(row + r) * N + col] = acc[i][j][r] * (rowscale[row + r] * s);
    }
  }
}

// ---------------- RoPE apply + reshape to q/k/vt bf16 -----------------------
__global__ __launch_bounds__(256) void ropeapply_k(const float* __restrict__ raw,
                                                   const float* __restrict__ cosT,
                                                   const float* __restrict__ sinT,
                                                   unsigned short* __restrict__ qb,
                                                   unsigned short* __restrict__ kb,
                                                   unsigned short* __restrict__ vtb) {
  int r = blockIdx.x;
  int b = r >> 11, s = r & 2047;
  const float* row = raw + (size_t)r * 3072;
  int tid = threadIdx.x;
  // Q: 16 heads x 64 pairs
  for (int idx = tid; idx < 1024; idx += 256) {
    int h = idx >> 6, d = idx & 63;
    float x1 = row[h * 128 + d], x2 = row[h * 128 + d + 64];
    float c = cosT[s * 64 + d], sn = sinT[s * 64 + d];
    size_t base = ((size_t)(b * 16 + h) * 2048 + s) * 128;
    qb[base + d]      = f2bf(x1 * c - x2 * sn);
    qb[base + d + 64] = f2bf(x2 * c + x1 * sn);
  }
  // K: 4 kv heads x 64 pairs = 256 entries
  {
    int h = tid >> 6, d = tid & 63;
    float x1 = row[2048 + h * 128 + d], x2 = row[2048 + h * 128 + d + 64];
    float c = cosT[s * 64 + d], sn = sinT[s * 64 + d];
    size_t base = ((size_t)(b * 4 + h) * 2048 + s) * 128;
    kb[base + d]      = f2bf(x1 * c - x2 * sn);
    kb[base + d + 64] = f2bf(x2 * c + x1 * sn);
  }
  // V transposed: vt[b][kv][d][s]
  for (int idx = tid; idx < 512; idx += 256) {
    int h = idx >> 7, d = idx & 127;
    vtb[((size_t)(b * 4 + h) * 128 + d) * 2048 + s] = f2bf(row[2560 + idx]);
  }
}

// ---------------- causal flash attention ------------------------------------
// grid (32 qtiles, 16 heads, 2 batch) x 256.  Each wave: 16 q rows.
__global__ __launch_bounds__(256) void attn_k(const unsigned short* __restrict__ qb,
                                              const unsigned short* __restrict__ kb,
                                              const unsigned short* __restrict__ vtb,
                                              float* __restrict__ out) {
  int qt = blockIdx.x, h = blockIdx.y, b = blockIdx.z;
  int wv = threadIdx.x >> 6, lane = threadIdx.x & 63;
  int g = lane >> 4, li = lane & 15;
  int qbase = qt * 64 + wv * 16;
  int kh = h >> 2;
  const unsigned short* qp = qb + ((size_t)(b * 16 + h) * 2048) * 128;
  const unsigned short* kp = kb + ((size_t)(b * 4 + kh) * 2048) * 128;
  const unsigned short* vp = vtb + ((size_t)(b * 4 + kh) * 128) * 2048;

  bf16x8 qf[4];
  #pragma unroll
  for (int kk = 0; kk < 4; kk++)
    qf[kk] = *(const bf16x8*)&qp[(size_t)(qbase + li) * 128 + kk * 32 + g * 8];

  f32x4 oacc[8] = {};
  float mrun[4] = {-INFINITY, -INFINITY, -INFINITY, -INFINITY};
  float lrun[4] = {0.f, 0.f, 0.f, 0.f};

  __shared__ unsigned short plds[4][16][32];
  const float scale = 0.08838834764831845f;   // 1/sqrt(128)

  int ntile = (qbase + 47) >> 5;
  for (int t = 0; t < ntile; ++t) {
    int kv0 = t * 32;
    f32x4 s0 = {}, s1 = {};
    #pragma unroll
    for (int kk = 0; kk < 4; kk++) {
      bf16x8 k0 = *(const bf16x8*)&kp[(size_t)(kv0 + li) * 128 + kk * 32 + g * 8];
      bf16x8 k1 = *(const bf16x8*)&kp[(size_t)(kv0 + 16 + li) * 128 + kk * 32 + g * 8];
      s0 = mfma16(qf[kk], k0, s0);
      s1 = mfma16(qf[kk], k1, s1);
    }
    float p0[4], p1[4], mx[4];
    #pragma unroll
    for (int r = 0; r < 4; r++) {
      int qg = qbase + g * 4 + r;
      float v0 = s0[r] * scale, v1 = s1[r] * scale;
      if (kv0 + li > qg)      v0 = -INFINITY;
      if (kv0 + 16 + li > qg) v1 = -INFINITY;
      p0[r] = v0; p1[r] = v1;
      mx[r] = fmaxf(v0, v1);
    }
    #pragma unroll
    for (int o = 1; o < 16; o <<= 1)
      #pragma unroll
      for (int r = 0; r < 4; r++) mx[r] = fmaxf(mx[r], __shfl_xor(mx[r], o));
    float alpha[4], rsum[4];
    #pragma unroll
    for (int r = 0; r < 4; r++) {
      float mnew = fmaxf(mrun[r], mx[r]);
      alpha[r] = expf(mrun[r] - mnew);
      p0[r] = expf(p0[r] - mnew);
      p1[r] = expf(p1[r] - mnew);
      mrun[r] = mnew;
      rsum[r] = p0[r] + p1[r];
    }
    #pragma unroll
    for (int o = 1; o < 16; o <<= 1)
      #pragma unroll
      for (int r = 0; r < 4; r++) rsum[r] += __shfl_xor(rsum[r], o);
    #pragma unroll
    for (int r = 0; r < 4; r++) lrun[r] = lrun[r] * alpha[r] + rsum[r];
    #pragma unroll
    for (int dn = 0; dn < 8; dn++)
      #pragma unroll
      for (int r = 0; r < 4; r++) oacc[dn][r] *= alpha[r];
    // P -> LDS (wave-private tile), re-read in A-frag layout
    #pragma unroll
    for (int r = 0; r < 4; r++) {
      plds[wv][g * 4 + r][li]      = f2bf(p0[r]);
      plds[wv][g * 4 + r][li + 16] = f2bf(p1[r]);
    }
    __builtin_amdgcn_wave_barrier();
    bf16x8 pa = *(const bf16x8*)&plds[wv][li][g * 8];
    #pragma unroll
    for (int dn = 0; dn < 8; dn++) {
      bf16x8 vf = *(const bf16x8*)&vp[(size_t)(dn * 16 + li) * 2048 + kv0 + g * 8];
      oacc[dn] = mfma16(pa, vf, oacc[dn]);
    }
    __builtin_amdgcn_wave_barrier();
  }
  float invl[4];
  #pragma unroll
  for (int r = 0; r < 4; r++) invl[r] = 1.0f / lrun[r];
  size_t obase = ((size_t)(b * 2048 + qbase + g * 4)) * 2048 + h * 128;
  #pragma unroll
  for (int dn = 0; dn < 8; dn++)
    #pragma unroll
    for (int r = 0; r < 4; r++)
      out[obase + (size_t)r * 2048 + dn * 16 + li] = oacc[dn][r] * invl[r];
}

// ---------------------------------------------------------------------------
extern "C" void kernel_launch(void* const* d_in, const int* in_sizes, int n_in,
                              void* d_out, int out_size, void* d_ws, size_t ws_size,
                              hipStream_t stream) {
  const float* x  = (const float*)d_in[0];
  const float* Wq = (const float*)d_in[1];
  const float* Wk = (const float*)d_in[2];
  const float* Wv = (const float*)d_in[3];
  const float* Wo = (const float*)d_in[4];
  float* out = (float*)d_out;

  char* ws = (char*)d_ws;
  size_t off = 0;
  auto alloc = [&](size_t bytes) -> void* {
    void* p = ws + off;
    off = (off + bytes + 255) & ~(size_t)255;
    return p;
  };
  float* sums = (float*)alloc(16);
  float* sw   = (float*)alloc(16);
  float* rs   = (float*)alloc(4096 * 4);
  float* rs2  = (float*)alloc(4096 * 4);
  float* cosT = (float*)alloc((size_t)131072 * 4);
  float* sinT = (float*)alloc((size_t)131072 * 4);
  unsigned short* Wcat = (unsigned short*)alloc((size_t)3072 * 2048 * 2);
  unsigned short* Wot  = (unsigned short*)alloc((size_t)2048 * 2048 * 2);
  unsigned short* qb   = (unsigned short*)alloc((size_t)2 * 16 * 2048 * 128 * 2);
  unsigned short* kb   = (unsigned short*)alloc((size_t)2 * 4 * 2048 * 128 * 2);
  unsigned short* vtb  = (unsigned short*)alloc((size_t)2 * 4 * 128 * 2048 * 2);
  unsigned short* xq   = (unsigned short*)alloc((size_t)4096 * 2048 * 2);
  float* raw  = (float*)alloc((size_t)4096 * 3072 * 4);
  float* attn = raw;   // reuse: raw dead after ropeapply_k

  hipMemsetAsync(sums, 0, 16, stream);
  absum_k<<<256, 256, 0, stream>>>(Wq, (long)2048 * 2048 / 4, sums + 0);
  absum_k<<<128, 256, 0, stream>>>(Wk, (long)512 * 2048 / 4, sums + 1);
  absum_k<<<128, 256, 0, stream>>>(Wv, (long)512 * 2048 / 4, sums + 2);
  absum_k<<<256, 256, 0, stream>>>(Wo, (long)2048 * 2048 / 4, sums + 3);
  finalize_k<<<1, 4, 0, stream>>>(sums, sw);
  quantw_k<<<512, 256, 0, stream>>>(Wq, Wcat, (long)2048 * 2048 / 4, sw + 0);
  quantw_k<<<128, 256, 0, stream>>>(Wk, Wcat + (size_t)2048 * 2048, (long)512 * 2048 / 4, sw + 1);
  quantw_k<<<128, 256, 0, stream>>>(Wv, Wcat + (size_t)2560 * 2048, (long)512 * 2048 / 4, sw + 2);
  quantw_k<<<512, 256, 0, stream>>>(Wo, Wot, (long)2048 * 2048 / 4, sw + 3);
  ropetab_k<<<512, 256, 0, stream>>>(cosT, sinT);
  quanta_k<<<4096, 256, 0, stream>>>(x, xq, rs);
  dim3 g1(3072 / 128, 4096 / 128);
  gemm_k<<<g1, 256, 0, stream>>>(xq, Wcat, raw, 4096, 3072, 2048, rs, sw, 0);
  ropeapply_k<<<4096, 256, 0, stream>>>(raw, cosT, sinT, qb, kb, vtb);
  attn_k<<<dim3(32, 16, 2), 256, 0, stream>>>(qb, kb, vtb, attn);
  quanta_k<<<4096, 256, 0, stream>>>(attn, xq, rs2);
  dim3 g2(2048 / 128, 4096 / 128);
  gemm_k<<<g2, 256, 0, stream>>>(xq, Wot, out, 4096, 2048, 2048, rs2, sw, 1);
}

// Round 2
// 404.339 us; speedup vs baseline: 2.0859x; 2.0859x over previous
//
#include <hip/hip_runtime.h>
#include <hip/hip_bf16.h>
#include <stdint.h>

typedef __bf16 bf16x8 __attribute__((ext_vector_type(8)));
typedef float f32x4 __attribute__((ext_vector_type(4)));
typedef unsigned short u16x8 __attribute__((ext_vector_type(8)));
typedef unsigned short u16x4 __attribute__((ext_vector_type(4)));

__device__ __forceinline__ unsigned short f2bf(float f) {
  union { float f; unsigned int u; } v; v.f = f;
  unsigned int r = v.u + 0x7fffu + ((v.u >> 16) & 1u);   // RNE
  return (unsigned short)(r >> 16);
}

__device__ __forceinline__ f32x4 mfma16(bf16x8 a, bf16x8 b, f32x4 c) {
  return __builtin_amdgcn_mfma_f32_16x16x32_bf16(a, b, c, 0, 0, 0);
}

__device__ __forceinline__ void gload_lds16(const void* g, void* l) {
  __builtin_amdgcn_global_load_lds(
      (const __attribute__((address_space(1))) void*)g,
      (__attribute__((address_space(3))) void*)l, 16, 0, 0);
}

// ---------------- abs-sum reduction (for absmean weight scale) --------------
__global__ void absum_k(const float* __restrict__ w, long n4, float* __restrict__ out) {
  long i = (long)blockIdx.x * blockDim.x + threadIdx.x;
  long stride = (long)gridDim.x * blockDim.x;
  const float4* w4 = (const float4*)w;
  float s = 0.f;
  for (; i < n4; i += stride) {
    float4 v = w4[i];
    s += fabsf(v.x) + fabsf(v.y) + fabsf(v.z) + fabsf(v.w);
  }
  #pragma unroll
  for (int o = 32; o; o >>= 1) s += __shfl_down(s, o);
  __shared__ float sm[4];
  int lane = threadIdx.x & 63, wv = threadIdx.x >> 6;
  if (lane == 0) sm[wv] = s;
  __syncthreads();
  if (threadIdx.x == 0) atomicAdd(out, sm[0] + sm[1] + sm[2] + sm[3]);
}

__global__ void finalize_k(const float* __restrict__ sums, float* __restrict__ sw) {
  int i = threadIdx.x;
  if (i < 4) {
    const float inv[4] = {1.f/(2048.f*2048.f), 1.f/(512.f*2048.f),
                          1.f/(512.f*2048.f), 1.f/(2048.f*2048.f)};
    sw[i] = sums[i] * inv[i] + 1e-5f;
  }
}

// ---------------- ternary weight quantization (store bf16 {-1,0,1}) ---------
__global__ void quantw_k(const float* __restrict__ w, unsigned short* __restrict__ o,
                         long n4, const float* __restrict__ swp) {
  float sw = *swp;
  long i = (long)blockIdx.x * blockDim.x + threadIdx.x;
  long stride = (long)gridDim.x * blockDim.x;
  const float4* w4 = (const float4*)w;
  u16x4* o4 = (u16x4*)o;
  for (; i < n4; i += stride) {
    float4 v = w4[i];
    u16x4 t;
    t[0] = f2bf(fminf(fmaxf(rintf(v.x / sw), -1.f), 1.f));
    t[1] = f2bf(fminf(fmaxf(rintf(v.y / sw), -1.f), 1.f));
    t[2] = f2bf(fminf(fmaxf(rintf(v.z / sw), -1.f), 1.f));
    t[3] = f2bf(fminf(fmaxf(rintf(v.w / sw), -1.f), 1.f));
    o4[i] = t;
  }
}

// ---------------- RoPE tables [2048][64] ------------------------------------
__global__ void ropetab_k(float* __restrict__ cosT, float* __restrict__ sinT) {
  int idx = blockIdx.x * 256 + threadIdx.x;
  int s = idx >> 6, d = idx & 63;
  float freq = expf(-(float)d * (9.210340371976184f / 64.0f));
  float ang = (float)s * freq;
  cosT[idx] = cosf(ang);
  sinT[idx] = sinf(ang);
}

// ---------------- activation quantization (per-row absmax, 8-bit) -----------
__global__ __launch_bounds__(256) void quanta_k(const float* __restrict__ x,
                                                unsigned short* __restrict__ xq,
                                                float* __restrict__ rs) {
  int row = blockIdx.x;
  const float* xr = x + (size_t)row * 2048;
  int tid = threadIdx.x;
  float4 v0 = ((const float4*)xr)[tid * 2];
  float4 v1 = ((const float4*)xr)[tid * 2 + 1];
  float m = fmaxf(fmaxf(fmaxf(fabsf(v0.x), fabsf(v0.y)), fmaxf(fabsf(v0.z), fabsf(v0.w))),
                  fmaxf(fmaxf(fabsf(v1.x), fabsf(v1.y)), fmaxf(fabsf(v1.z), fabsf(v1.w))));
  #pragma unroll
  for (int o = 32; o; o >>= 1) m = fmaxf(m, __shfl_xor(m, o));
  __shared__ float sm[4];
  if ((tid & 63) == 0) sm[tid >> 6] = m;
  __syncthreads();
  m = fmaxf(fmaxf(sm[0], sm[1]), fmaxf(sm[2], sm[3]));
  float rm = fmaxf(m, 1e-5f);
  float sx = 127.0f / rm;
  float vv[8] = {v0.x, v0.y, v0.z, v0.w, v1.x, v1.y, v1.z, v1.w};
  u16x8 o8;
  #pragma unroll
  for (int j = 0; j < 8; j++) {
    float r = rintf(vv[j] * sx);
    r = fminf(fmaxf(r, -128.f), 127.f);
    o8[j] = f2bf(r);
  }
  ((u16x8*)(xq + (size_t)row * 2048))[tid] = o8;
  if (tid == 0) rs[row] = rm * (1.0f / 127.0f);
}

// ---------------- GEMM (m97 structure): C = scale*(A . Bt^T) ----------------
__global__ __launch_bounds__(256) void gemm_k(const unsigned short* __restrict__ A,
                                              const unsigned short* __restrict__ Bt,
                                              float* __restrict__ C,
                                              int M, int N, int K,
                                              const float* __restrict__ rowscale,
                                              const float* __restrict__ sw, int mode) {
  __shared__ unsigned short As[128 * 32];
  __shared__ unsigned short Bs[128 * 32];
  int tid = threadIdx.x;
  int lane = tid & 63, wv = tid >> 6;
  int g = lane >> 4, li = lane & 15;
  int wm = wv >> 1, wn = wv & 1;
  int m0 = blockIdx.y * 128, n0 = blockIdx.x * 128;
  int sr = lane >> 2;         // staging row within 16-row group
  int sc = lane & 3;          // staging 16B-chunk within row (row = 64B)
  int gc = (sc ^ ((sr >> 1) & 3)) * 8;   // pre-swizzled global chunk
  int swz = (g ^ ((li >> 1) & 3)) * 8;   // swizzled read chunk
  f32x4 acc[4][4] = {};

  for (int k0 = 0; k0 < K; k0 += 32) {
    __syncthreads();
    #pragma unroll
    for (int j = 0; j < 2; j++) {
      int row = (wv * 2 + j) * 16 + sr;
      gload_lds16(&A[(size_t)(m0 + row) * K + k0 + gc], &As[(wv * 2 + j) * 512]);
      gload_lds16(&Bt[(size_t)(n0 + row) * K + k0 + gc], &Bs[(wv * 2 + j) * 512]);
    }
    __syncthreads();
    bf16x8 af[4], bfr[4];
    #pragma unroll
    for (int i = 0; i < 4; i++)
      af[i] = *(const bf16x8*)&As[(wm * 64 + i * 16 + li) * 32 + swz];
    #pragma unroll
    for (int j = 0; j < 4; j++)
      bfr[j] = *(const bf16x8*)&Bs[(wn * 64 + j * 16 + li) * 32 + swz];
    #pragma unroll
    for (int i = 0; i < 4; i++)
      #pragma unroll
      for (int j = 0; j < 4; j++)
        acc[i][j] = mfma16(af[i], bfr[j], acc[i][j]);
  }

  #pragma unroll
  for (int i = 0; i < 4; i++) {
    int row = m0 + wm * 64 + i * 16 + g * 4;
    #pragma unroll
    for (int j = 0; j < 4; j++) {
      int col = n0 + wn * 64 + j * 16 + li;
      float s = (mode == 0) ? ((col < 2048) ? sw[0] : (col < 2560 ? sw[1] : sw[2]))
                            : sw[3];
      #pragma unroll
      for (int r = 0; r < 4; r++)
        C[(size_t)(row + r) * N + col] = acc[i][j][r] * (rowscale[row + r] * s);
    }
  }
}

// ---------------- RoPE apply + reshape to q/k/vt bf16 -----------------------
__global__ __launch_bounds__(256) void ropeapply_k(const float* __restrict__ raw,
                                                   const float* __restrict__ cosT,
                                                   const float* __restrict__ sinT,
                                                   unsigned short* __restrict__ qb,
                                                   unsigned short* __restrict__ kb,
                                                   unsigned short* __restrict__ vtb) {
  int r = blockIdx.x;
  int b = r >> 11, s = r & 2047;
  const float* row = raw + (size_t)r * 3072;
  int tid = threadIdx.x;
  for (int idx = tid; idx < 1024; idx += 256) {
    int h = idx >> 6, d = idx & 63;
    float x1 = row[h * 128 + d], x2 = row[h * 128 + d + 64];
    float c = cosT[s * 64 + d], sn = sinT[s * 64 + d];
    size_t base = ((size_t)(b * 16 + h) * 2048 + s) * 128;
    qb[base + d]      = f2bf(x1 * c - x2 * sn);
    qb[base + d + 64] = f2bf(x2 * c + x1 * sn);
  }
  {
    int h = tid >> 6, d = tid & 63;
    float x1 = row[2048 + h * 128 + d], x2 = row[2048 + h * 128 + d + 64];
    float c = cosT[s * 64 + d], sn = sinT[s * 64 + d];
    size_t base = ((size_t)(b * 4 + h) * 2048 + s) * 128;
    kb[base + d]      = f2bf(x1 * c - x2 * sn);
    kb[base + d + 64] = f2bf(x2 * c + x1 * sn);
  }
  for (int idx = tid; idx < 512; idx += 256) {
    int h = idx >> 7, d = idx & 127;
    vtb[((size_t)(b * 4 + h) * 128 + d) * 2048 + s] = f2bf(row[2560 + idx]);
  }
}

// ---------------- causal flash attention (fold-balanced, LDS-staged) --------
// grid (16 fold-pairs, 16 heads, 2 batch) x 256. Wave: 16 q rows. KVBLK=64.
__global__ __launch_bounds__(256) void attn_k(const unsigned short* __restrict__ qb,
                                              const unsigned short* __restrict__ kb,
                                              const unsigned short* __restrict__ vtb,
                                              float* __restrict__ out) {
  int h = blockIdx.y, b = blockIdx.z;
  int wv = threadIdx.x >> 6, lane = threadIdx.x & 63;
  int g = lane >> 4, li = lane & 15;
  int kh = h >> 2;
  const unsigned short* qp = qb + ((size_t)(b * 16 + h) * 2048) * 128;
  const unsigned short* kp = kb + ((size_t)(b * 4 + kh) * 2048) * 128;
  const unsigned short* vp = vtb + ((size_t)(b * 4 + kh) * 128) * 2048;

  __shared__ unsigned short Ks[64 * 128];   // [kv][d], chunks XOR-swizzled by kv&7
  __shared__ unsigned short Vs[128 * 64];   // [d][kv], chunks XOR-swizzled by d&7
  __shared__ unsigned short Pl[4][16][72];  // wave-private P tile, padded

  const float cs = 0.1275356234f;  // log2(e)/sqrt(128)

  #pragma unroll 1
  for (int part = 0; part < 2; ++part) {
    int tq = part ? (31 - blockIdx.x) : blockIdx.x;
    int qw = tq * 64 + wv * 16;
    bf16x8 qf[4];
    #pragma unroll
    for (int kk = 0; kk < 4; kk++)
      qf[kk] = *(const bf16x8*)&qp[(size_t)(qw + li) * 128 + kk * 32 + g * 8];
    f32x4 oacc[8] = {};
    float mrun = -INFINITY, lrun = 0.f;
    int nt = tq + 1;
    for (int t = 0; t < nt; ++t) {
      int kv0 = t * 64;
      __syncthreads();
      // stage K tile: 4 rows/instr, pre-swizzled source columns
      #pragma unroll
      for (int i = 0; i < 4; i++) {
        int r = wv * 16 + i * 4 + g;                 // tile-local kv row
        gload_lds16(kp + (size_t)(kv0 + r) * 128 + ((li ^ (r & 7)) * 8),
                    &Ks[(wv * 16 + i * 4) * 128]);
      }
      // stage V^T tile: 8 rows/instr (row = 64 kv = 128B)
      #pragma unroll
      for (int i = 0; i < 4; i++) {
        int d = wv * 32 + i * 8 + (lane >> 3);
        int c = lane & 7;
        gload_lds16(vp + (size_t)d * 2048 + kv0 + ((c ^ (d & 7)) * 8),
                    &Vs[(wv * 32 + i * 8) * 64]);
      }
      __syncthreads();
      // QK^T swapped: st[n] = K_sub(n) x Q^T -> lane holds S[kv=g*4+r][q=li]
      f32x4 st[4] = {};
      #pragma unroll
      for (int kk = 0; kk < 4; kk++) {
        #pragma unroll
        for (int n = 0; n < 4; n++) {
          bf16x8 kf = *(const bf16x8*)&Ks[(n * 16 + li) * 128 +
                                          (((kk * 4 + g) ^ (li & 7)) * 8)];
          st[n] = mfma16(kf, qf[kk], st[n]);
        }
      }
      // scale + causal mask (mask only possible on last tile)
      int qrel = (t == nt - 1) ? (qw + li - kv0) : (1 << 30);
      float mx = -INFINITY;
      #pragma unroll
      for (int n = 0; n < 4; n++)
        #pragma unroll
        for (int r = 0; r < 4; r++) {
          float v = st[n][r] * cs;
          v = ((n * 16 + g * 4 + r) > qrel) ? -INFINITY : v;
          st[n][r] = v;
          mx = fmaxf(mx, v);
        }
      mx = fmaxf(mx, __shfl_xor(mx, 16));
      mx = fmaxf(mx, __shfl_xor(mx, 32));
      float mnew = fmaxf(mrun, mx);
      float alpha = exp2f(mrun - mnew);
      float lsum = 0.f;
      #pragma unroll
      for (int n = 0; n < 4; n++) {
        u16x4 pw;
        #pragma unroll
        for (int r = 0; r < 4; r++) {
          float p = exp2f(st[n][r] - mnew);
          lsum += p;
          pw[r] = f2bf(p);
        }
        *(u16x4*)&Pl[wv][li][n * 16 + g * 4] = pw;
      }
      lsum += __shfl_xor(lsum, 16);
      lsum += __shfl_xor(lsum, 32);
      lrun = lrun * alpha + lsum;
      mrun = mnew;
      if (__any(alpha != 1.0f)) {
        float ar[4];
        #pragma unroll
        for (int r = 0; r < 4; r++) ar[r] = __shfl(alpha, g * 4 + r, 64);
        #pragma unroll
        for (int dn = 0; dn < 8; dn++)
          #pragma unroll
          for (int r = 0; r < 4; r++) oacc[dn][r] *= ar[r];
      }
      __builtin_amdgcn_wave_barrier();
      bf16x8 pa0 = *(const bf16x8*)&Pl[wv][li][g * 8];
      bf16x8 pa1 = *(const bf16x8*)&Pl[wv][li][32 + g * 8];
      #pragma unroll
      for (int dn = 0; dn < 8; dn++) {
        int d = dn * 16 + li;
        bf16x8 vf0 = *(const bf16x8*)&Vs[d * 64 + ((g ^ (li & 7)) * 8)];
        bf16x8 vf1 = *(const bf16x8*)&Vs[d * 64 + (((4 + g) ^ (li & 7)) * 8)];
        oacc[dn] = mfma16(pa0, vf0, oacc[dn]);
        oacc[dn] = mfma16(pa1, vf1, oacc[dn]);
      }
      __builtin_amdgcn_wave_barrier();
    }
    float linv = 1.0f / lrun;
    float lr_[4];
    #pragma unroll
    for (int r = 0; r < 4; r++) lr_[r] = __shfl(linv, g * 4 + r, 64);
    size_t obase = ((size_t)(b * 2048 + qw + g * 4)) * 2048 + h * 128;
    #pragma unroll
    for (int dn = 0; dn < 8; dn++)
      #pragma unroll
      for (int r = 0; r < 4; r++)
        out[obase + (size_t)r * 2048 + dn * 16 + li] = oacc[dn][r] * lr_[r];
  }
}

// ---------------------------------------------------------------------------
extern "C" void kernel_launch(void* const* d_in, const int* in_sizes, int n_in,
                              void* d_out, int out_size, void* d_ws, size_t ws_size,
                              hipStream_t stream) {
  const float* x  = (const float*)d_in[0];
  const float* Wq = (const float*)d_in[1];
  const float* Wk = (const float*)d_in[2];
  const float* Wv = (const float*)d_in[3];
  const float* Wo = (const float*)d_in[4];
  float* out = (float*)d_out;

  char* ws = (char*)d_ws;
  size_t off = 0;
  auto alloc = [&](size_t bytes) -> void* {
    void* p = ws + off;
    off = (off + bytes + 255) & ~(size_t)255;
    return p;
  };
  float* sums = (float*)alloc(16);
  float* sw   = (float*)alloc(16);
  float* rs   = (float*)alloc(4096 * 4);
  float* rs2  = (float*)alloc(4096 * 4);
  float* cosT = (float*)alloc((size_t)131072 * 4);
  float* sinT = (float*)alloc((size_t)131072 * 4);
  unsigned short* Wcat = (unsigned short*)alloc((size_t)3072 * 2048 * 2);
  unsigned short* Wot  = (unsigned short*)alloc((size_t)2048 * 2048 * 2);
  unsigned short* qb   = (unsigned short*)alloc((size_t)2 * 16 * 2048 * 128 * 2);
  unsigned short* kb   = (unsigned short*)alloc((size_t)2 * 4 * 2048 * 128 * 2);
  unsigned short* vtb  = (unsigned short*)alloc((size_t)2 * 4 * 128 * 2048 * 2);
  unsigned short* xq   = (unsigned short*)alloc((size_t)4096 * 2048 * 2);
  float* raw  = (float*)alloc((size_t)4096 * 3072 * 4);
  float* attn = raw;   // reuse: raw dead after ropeapply_k

  hipMemsetAsync(sums, 0, 16, stream);
  absum_k<<<256, 256, 0, stream>>>(Wq, (long)2048 * 2048 / 4, sums + 0);
  absum_k<<<128, 256, 0, stream>>>(Wk, (long)512 * 2048 / 4, sums + 1);
  absum_k<<<128, 256, 0, stream>>>(Wv, (long)512 * 2048 / 4, sums + 2);
  absum_k<<<256, 256, 0, stream>>>(Wo, (long)2048 * 2048 / 4, sums + 3);
  finalize_k<<<1, 4, 0, stream>>>(sums, sw);
  quantw_k<<<512, 256, 0, stream>>>(Wq, Wcat, (long)2048 * 2048 / 4, sw + 0);
  quantw_k<<<128, 256, 0, stream>>>(Wk, Wcat + (size_t)2048 * 2048, (long)512 * 2048 / 4, sw + 1);
  quantw_k<<<128, 256, 0, stream>>>(Wv, Wcat + (size_t)2560 * 2048, (long)512 * 2048 / 4, sw + 2);
  quantw_k<<<512, 256, 0, stream>>>(Wo, Wot, (long)2048 * 2048 / 4, sw + 3);
  ropetab_k<<<512, 256, 0, stream>>>(cosT, sinT);
  quanta_k<<<4096, 256, 0, stream>>>(x, xq, rs);
  dim3 g1(3072 / 128, 4096 / 128);
  gemm_k<<<g1, 256, 0, stream>>>(xq, Wcat, raw, 4096, 3072, 2048, rs, sw, 0);
  ropeapply_k<<<4096, 256, 0, stream>>>(raw, cosT, sinT, qb, kb, vtb);
  attn_k<<<dim3(16, 16, 2), 256, 0, stream>>>(qb, kb, vtb, attn);
  quanta_k<<<4096, 256, 0, stream>>>(attn, xq, rs2);
  dim3 g2(2048 / 128, 4096 / 128);
  gemm_k<<<g2, 256, 0, stream>>>(xq, Wot, out, 4096, 2048, 2048, rs2, sw, 1);
}

// Round 3
// 386.572 us; speedup vs baseline: 2.1818x; 1.0460x over previous
//
#include <hip/hip_runtime.h>
#include <hip/hip_bf16.h>
#include <stdint.h>

typedef __bf16 bf16x8 __attribute__((ext_vector_type(8)));
typedef __bf16 bf16x4v __attribute__((ext_vector_type(4)));
typedef float f32x4 __attribute__((ext_vector_type(4)));
typedef unsigned short u16x8 __attribute__((ext_vector_type(8)));
typedef unsigned short u16x4 __attribute__((ext_vector_type(4)));

__device__ __forceinline__ unsigned short f2bf(float f) {
  union { float f; unsigned int u; } v; v.f = f;
  unsigned int r = v.u + 0x7fffu + ((v.u >> 16) & 1u);   // RNE
  return (unsigned short)(r >> 16);
}

__device__ __forceinline__ f32x4 mfma16(bf16x8 a, bf16x8 b, f32x4 c) {
  return __builtin_amdgcn_mfma_f32_16x16x32_bf16(a, b, c, 0, 0, 0);
}

__device__ __forceinline__ void gload_lds16(const void* g, void* l) {
  __builtin_amdgcn_global_load_lds(
      (const __attribute__((address_space(1))) void*)g,
      (__attribute__((address_space(3))) void*)l, 16, 0, 0);
}

// ---------------- abs-sum reduction (for absmean weight scale) --------------
__global__ void absum_k(const float* __restrict__ w, long n4, float* __restrict__ out) {
  long i = (long)blockIdx.x * blockDim.x + threadIdx.x;
  long stride = (long)gridDim.x * blockDim.x;
  const float4* w4 = (const float4*)w;
  float s = 0.f;
  for (; i < n4; i += stride) {
    float4 v = w4[i];
    s += fabsf(v.x) + fabsf(v.y) + fabsf(v.z) + fabsf(v.w);
  }
  #pragma unroll
  for (int o = 32; o; o >>= 1) s += __shfl_down(s, o);
  __shared__ float sm[4];
  int lane = threadIdx.x & 63, wv = threadIdx.x >> 6;
  if (lane == 0) sm[wv] = s;
  __syncthreads();
  if (threadIdx.x == 0) atomicAdd(out, sm[0] + sm[1] + sm[2] + sm[3]);
}

__global__ void finalize_k(const float* __restrict__ sums, float* __restrict__ sw) {
  int i = threadIdx.x;
  if (i < 4) {
    const float inv[4] = {1.f/(2048.f*2048.f), 1.f/(512.f*2048.f),
                          1.f/(512.f*2048.f), 1.f/(2048.f*2048.f)};
    sw[i] = sums[i] * inv[i] + 1e-5f;
  }
}

// ---------------- ternary weight quantization (store bf16 {-1,0,1}) ---------
__global__ void quantw_k(const float* __restrict__ w, unsigned short* __restrict__ o,
                         long n4, const float* __restrict__ swp) {
  float sw = *swp;
  long i = (long)blockIdx.x * blockDim.x + threadIdx.x;
  long stride = (long)gridDim.x * blockDim.x;
  const float4* w4 = (const float4*)w;
  u16x4* o4 = (u16x4*)o;
  for (; i < n4; i += stride) {
    float4 v = w4[i];
    u16x4 t;
    t[0] = f2bf(fminf(fmaxf(rintf(v.x / sw), -1.f), 1.f));
    t[1] = f2bf(fminf(fmaxf(rintf(v.y / sw), -1.f), 1.f));
    t[2] = f2bf(fminf(fmaxf(rintf(v.z / sw), -1.f), 1.f));
    t[3] = f2bf(fminf(fmaxf(rintf(v.w / sw), -1.f), 1.f));
    o4[i] = t;
  }
}

// ---------------- RoPE tables [2048][64] ------------------------------------
__global__ void ropetab_k(float* __restrict__ cosT, float* __restrict__ sinT) {
  int idx = blockIdx.x * 256 + threadIdx.x;
  int s = idx >> 6, d = idx & 63;
  float freq = expf(-(float)d * (9.210340371976184f / 64.0f));
  float ang = (float)s * freq;
  cosT[idx] = cosf(ang);
  sinT[idx] = sinf(ang);
}

// ---------------- activation quantization (per-row absmax, 8-bit) -----------
__global__ __launch_bounds__(256) void quanta_k(const float* __restrict__ x,
                                                unsigned short* __restrict__ xq,
                                                float* __restrict__ rs) {
  int row = blockIdx.x;
  const float* xr = x + (size_t)row * 2048;
  int tid = threadIdx.x;
  float4 v0 = ((const float4*)xr)[tid * 2];
  float4 v1 = ((const float4*)xr)[tid * 2 + 1];
  float m = fmaxf(fmaxf(fmaxf(fabsf(v0.x), fabsf(v0.y)), fmaxf(fabsf(v0.z), fabsf(v0.w))),
                  fmaxf(fmaxf(fabsf(v1.x), fabsf(v1.y)), fmaxf(fabsf(v1.z), fabsf(v1.w))));
  #pragma unroll
  for (int o = 32; o; o >>= 1) m = fmaxf(m, __shfl_xor(m, o));
  __shared__ float sm[4];
  if ((tid & 63) == 0) sm[tid >> 6] = m;
  __syncthreads();
  m = fmaxf(fmaxf(sm[0], sm[1]), fmaxf(sm[2], sm[3]));
  float rm = fmaxf(m, 1e-5f);
  float sx = 127.0f / rm;
  float vv[8] = {v0.x, v0.y, v0.z, v0.w, v1.x, v1.y, v1.z, v1.w};
  u16x8 o8;
  #pragma unroll
  for (int j = 0; j < 8; j++) {
    float r = rintf(vv[j] * sx);
    r = fminf(fmaxf(r, -128.f), 127.f);
    o8[j] = f2bf(r);
  }
  ((u16x8*)(xq + (size_t)row * 2048))[tid] = o8;
  if (tid == 0) rs[row] = rm * (1.0f / 127.0f);
}

// ---------------- GEMM (m97 structure + T1 XCD swizzle) ---------------------
__global__ __launch_bounds__(256) void gemm_k(const unsigned short* __restrict__ A,
                                              const unsigned short* __restrict__ Bt,
                                              float* __restrict__ C,
                                              int M, int N, int K,
                                              const float* __restrict__ rowscale,
                                              const float* __restrict__ sw, int mode) {
  __shared__ unsigned short As[128 * 32];
  __shared__ unsigned short Bs[128 * 32];
  int tid = threadIdx.x;
  int lane = tid & 63, wv = tid >> 6;
  int g = lane >> 4, li = lane & 15;
  int wm = wv >> 1, wn = wv & 1;
  // XCD-aware bijective swizzle (grids are multiples of 8)
  int L = blockIdx.x + gridDim.x * blockIdx.y;
  int nwg = gridDim.x * gridDim.y;
  int swz_id = (L & 7) * (nwg >> 3) + (L >> 3);
  int m0 = (swz_id / gridDim.x) * 128, n0 = (swz_id % gridDim.x) * 128;
  int sr = lane >> 2;
  int sc = lane & 3;
  int gc = (sc ^ ((sr >> 1) & 3)) * 8;
  int swz = (g ^ ((li >> 1) & 3)) * 8;
  f32x4 acc[4][4] = {};

  for (int k0 = 0; k0 < K; k0 += 32) {
    __syncthreads();
    #pragma unroll
    for (int j = 0; j < 2; j++) {
      int row = (wv * 2 + j) * 16 + sr;
      gload_lds16(&A[(size_t)(m0 + row) * K + k0 + gc], &As[(wv * 2 + j) * 512]);
      gload_lds16(&Bt[(size_t)(n0 + row) * K + k0 + gc], &Bs[(wv * 2 + j) * 512]);
    }
    __syncthreads();
    bf16x8 af[4], bfr[4];
    #pragma unroll
    for (int i = 0; i < 4; i++)
      af[i] = *(const bf16x8*)&As[(wm * 64 + i * 16 + li) * 32 + swz];
    #pragma unroll
    for (int j = 0; j < 4; j++)
      bfr[j] = *(const bf16x8*)&Bs[(wn * 64 + j * 16 + li) * 32 + swz];
    #pragma unroll
    for (int i = 0; i < 4; i++)
      #pragma unroll
      for (int j = 0; j < 4; j++)
        acc[i][j] = mfma16(af[i], bfr[j], acc[i][j]);
  }

  #pragma unroll
  for (int i = 0; i < 4; i++) {
    int row = m0 + wm * 64 + i * 16 + g * 4;
    #pragma unroll
    for (int j = 0; j < 4; j++) {
      int col = n0 + wn * 64 + j * 16 + li;
      float s = (mode == 0) ? ((col < 2048) ? sw[0] : (col < 2560 ? sw[1] : sw[2]))
                            : sw[3];
      #pragma unroll
      for (int r = 0; r < 4; r++)
        C[(size_t)(row + r) * N + col] = acc[i][j][r] * (rowscale[row + r] * s);
    }
  }
}

// ---------------- RoPE apply (Q pre-scaled by log2e/sqrt(128)) --------------
__global__ __launch_bounds__(256) void ropeapply_k(const float* __restrict__ raw,
                                                   const float* __restrict__ cosT,
                                                   const float* __restrict__ sinT,
                                                   unsigned short* __restrict__ qb,
                                                   unsigned short* __restrict__ kb) {
  const float CS = 0.1275356234f;  // log2(e)/sqrt(128)
  int r = blockIdx.x;
  int b = r >> 11, s = r & 2047;
  const float* row = raw + (size_t)r * 3072;
  int tid = threadIdx.x;
  for (int idx = tid; idx < 1024; idx += 256) {
    int h = idx >> 6, d = idx & 63;
    float x1 = row[h * 128 + d], x2 = row[h * 128 + d + 64];
    float c = cosT[s * 64 + d], sn = sinT[s * 64 + d];
    size_t base = ((size_t)(b * 16 + h) * 2048 + s) * 128;
    qb[base + d]      = f2bf((x1 * c - x2 * sn) * CS);
    qb[base + d + 64] = f2bf((x2 * c + x1 * sn) * CS);
  }
  {
    int h = tid >> 6, d = tid & 63;
    float x1 = row[2048 + h * 128 + d], x2 = row[2048 + h * 128 + d + 64];
    float c = cosT[s * 64 + d], sn = sinT[s * 64 + d];
    size_t base = ((size_t)(b * 4 + h) * 2048 + s) * 128;
    kb[base + d]      = f2bf(x1 * c - x2 * sn);
    kb[base + d + 64] = f2bf(x2 * c + x1 * sn);
  }
}

// ---------------- V transpose: raw[b][s][2560+hk*128+d] -> vtb[b][hk][d][s] -
__global__ __launch_bounds__(256) void transv_k(const float* __restrict__ raw,
                                                unsigned short* __restrict__ vtb) {
  __shared__ unsigned short T[128][136];
  int sc = blockIdx.x, hk = blockIdx.y, b = blockIdx.z;
  int tid = threadIdx.x;
  #pragma unroll
  for (int i = 0; i < 16; i++) {
    int idx4 = i * 256 + tid;
    int s = idx4 >> 5, d4 = idx4 & 31;
    float4 v = *(const float4*)&raw[((size_t)(b * 2048 + sc * 128 + s)) * 3072 +
                                    2560 + hk * 128 + d4 * 4];
    u16x4 t4;
    t4[0] = f2bf(v.x); t4[1] = f2bf(v.y); t4[2] = f2bf(v.z); t4[3] = f2bf(v.w);
    *(u16x4*)&T[s][d4 * 4] = t4;
  }
  __syncthreads();
  int d = tid >> 1, s0 = (tid & 1) * 64;
  size_t obase = ((size_t)(b * 4 + hk) * 128 + d) * 2048 + sc * 128 + s0;
  #pragma unroll
  for (int j = 0; j < 8; j++) {
    u16x8 o8;
    #pragma unroll
    for (int e = 0; e < 8; e++) o8[e] = T[s0 + j * 8 + e][d];
    *(u16x8*)&vtb[obase + j * 8] = o8;
  }
}

// ---------------- causal flash attention (dbuf + counted vmcnt) -------------
// grid (16 fold-pairs, 16 heads, 2 batch) x 256. Wave: 16 q rows. KVBLK=64.
__global__ __launch_bounds__(256) void attn_k(const unsigned short* __restrict__ qb,
                                              const unsigned short* __restrict__ kb,
                                              const unsigned short* __restrict__ vtb,
                                              float* __restrict__ out) {
  int h = blockIdx.y, b = blockIdx.z;
  int wv = threadIdx.x >> 6, lane = threadIdx.x & 63;
  int g = lane >> 4, li = lane & 15;
  int kh = h >> 2;
  const unsigned short* qp = qb + ((size_t)(b * 16 + h) * 2048) * 128;
  const unsigned short* kp = kb + ((size_t)(b * 4 + kh) * 2048) * 128;
  const unsigned short* vp = vtb + ((size_t)(b * 4 + kh) * 128) * 2048;

  __shared__ unsigned short Ks[2][64 * 128];
  __shared__ unsigned short Vs[2][128 * 64];
  __shared__ unsigned short Pl[4][16][72];

  #pragma unroll 1
  for (int part = 0; part < 2; ++part) {
    int tq = part ? (31 - (int)blockIdx.x) : (int)blockIdx.x;
    int qw = tq * 64 + wv * 16;
    bf16x8 qf[4];
    #pragma unroll
    for (int kk = 0; kk < 4; kk++)
      qf[kk] = *(const bf16x8*)&qp[(size_t)(qw + li) * 128 + kk * 32 + g * 8];
    f32x4 oacc[8] = {};
    float mrun = -INFINITY, lrun = 0.f;
    int nt = tq + 1;

    // prologue: stage tile 0 into buf 0 (8 loads/thread)
    {
      #pragma unroll
      for (int i = 0; i < 4; i++) {
        int r = wv * 16 + i * 4 + g;
        gload_lds16(kp + (size_t)r * 128 + ((li ^ (r & 7)) * 8),
                    &Ks[0][(wv * 16 + i * 4) * 128]);
      }
      #pragma unroll
      for (int i = 0; i < 4; i++) {
        int d = wv * 32 + i * 8 + (lane >> 3);
        gload_lds16(vp + (size_t)d * 2048 + (((lane & 7) ^ (d & 7)) * 8),
                    &Vs[0][(wv * 32 + i * 8) * 64]);
      }
    }

    #pragma unroll 1
    for (int t = 0; t < nt; ++t) {
      int cur = t & 1;
      if (t + 1 < nt) {
        int kv1 = (t + 1) * 64;
        #pragma unroll
        for (int i = 0; i < 4; i++) {
          int r = wv * 16 + i * 4 + g;
          gload_lds16(kp + (size_t)(kv1 + r) * 128 + ((li ^ (r & 7)) * 8),
                      &Ks[cur ^ 1][(wv * 16 + i * 4) * 128]);
        }
        #pragma unroll
        for (int i = 0; i < 4; i++) {
          int d = wv * 32 + i * 8 + (lane >> 3);
          gload_lds16(vp + (size_t)d * 2048 + kv1 + (((lane & 7) ^ (d & 7)) * 8),
                      &Vs[cur ^ 1][(wv * 32 + i * 8) * 64]);
        }
        asm volatile("s_waitcnt vmcnt(8)" ::: "memory");
      } else {
        asm volatile("s_waitcnt vmcnt(0)" ::: "memory");
      }
      __builtin_amdgcn_s_barrier();
      asm volatile("" ::: "memory");

      // QK^T swapped: lane holds S[kv = n*16+g*4+r][q = li] (log2-domain)
      f32x4 st[4] = {};
      #pragma unroll
      for (int kk = 0; kk < 4; kk++) {
        #pragma unroll
        for (int n = 0; n < 4; n++) {
          bf16x8 kf = *(const bf16x8*)&Ks[cur][(n * 16 + li) * 128 +
                                              (((kk * 4 + g) ^ (li & 7)) * 8)];
          st[n] = mfma16(kf, qf[kk], st[n]);
        }
      }
      if (t == nt - 1) {   // causal mask only on diagonal tile
        int qrel = qw + li - t * 64;
        #pragma unroll
        for (int n = 0; n < 4; n++)
          #pragma unroll
          for (int r = 0; r < 4; r++)
            if ((n * 16 + g * 4 + r) > qrel) st[n][r] = -INFINITY;
      }
      float mx = st[0][0];
      #pragma unroll
      for (int n = 0; n < 4; n++)
        #pragma unroll
        for (int r = 0; r < 4; r++) mx = fmaxf(mx, st[n][r]);
      mx = fmaxf(mx, __shfl_xor(mx, 16));
      mx = fmaxf(mx, __shfl_xor(mx, 32));
      float mnew = fmaxf(mrun, mx);
      float alpha = exp2f(mrun - mnew);
      float lsum = 0.f;
      #pragma unroll
      for (int n = 0; n < 4; n++) {
        bf16x4v pw;
        #pragma unroll
        for (int r = 0; r < 4; r++) {
          float p = exp2f(st[n][r] - mnew);
          lsum += p;
          pw[r] = (__bf16)p;
        }
        *(bf16x4v*)&Pl[wv][li][n * 16 + g * 4] = pw;
      }
      lsum += __shfl_xor(lsum, 16);
      lsum += __shfl_xor(lsum, 32);
      lrun = lrun * alpha + lsum;
      mrun = mnew;
      if (__any(alpha != 1.0f)) {
        float ar[4];
        #pragma unroll
        for (int r = 0; r < 4; r++) ar[r] = __shfl(alpha, g * 4 + r, 64);
        #pragma unroll
        for (int dn = 0; dn < 8; dn++)
          #pragma unroll
          for (int r = 0; r < 4; r++) oacc[dn][r] *= ar[r];
      }
      __builtin_amdgcn_wave_barrier();
      bf16x8 pa0 = *(const bf16x8*)&Pl[wv][li][g * 8];
      bf16x8 pa1 = *(const bf16x8*)&Pl[wv][li][32 + g * 8];
      #pragma unroll
      for (int dn = 0; dn < 8; dn++) {
        int d = dn * 16 + li;
        bf16x8 vf0 = *(const bf16x8*)&Vs[cur][d * 64 + ((g ^ (li & 7)) * 8)];
        bf16x8 vf1 = *(const bf16x8*)&Vs[cur][d * 64 + (((4 + g) ^ (li & 7)) * 8)];
        oacc[dn] = mfma16(pa0, vf0, oacc[dn]);
        oacc[dn] = mfma16(pa1, vf1, oacc[dn]);
      }
      __builtin_amdgcn_wave_barrier();
      asm volatile("" ::: "memory");
      __builtin_amdgcn_s_barrier();   // all waves done reading buf[cur]
      asm volatile("" ::: "memory");
    }
    float linv = 1.0f / lrun;
    float lr_[4];
    #pragma unroll
    for (int r = 0; r < 4; r++) lr_[r] = __shfl(linv, g * 4 + r, 64);
    size_t obase = ((size_t)(b * 2048 + qw + g * 4)) * 2048 + h * 128;
    #pragma unroll
    for (int dn = 0; dn < 8; dn++)
      #pragma unroll
      for (int r = 0; r < 4; r++)
        out[obase + (size_t)r * 2048 + dn * 16 + li] = oacc[dn][r] * lr_[r];
  }
}

// ---------------------------------------------------------------------------
extern "C" void kernel_launch(void* const* d_in, const int* in_sizes, int n_in,
                              void* d_out, int out_size, void* d_ws, size_t ws_size,
                              hipStream_t stream) {
  const float* x  = (const float*)d_in[0];
  const float* Wq = (const float*)d_in[1];
  const float* Wk = (const float*)d_in[2];
  const float* Wv = (const float*)d_in[3];
  const float* Wo = (const float*)d_in[4];
  float* out = (float*)d_out;

  char* ws = (char*)d_ws;
  size_t off = 0;
  auto alloc = [&](size_t bytes) -> void* {
    void* p = ws + off;
    off = (off + bytes + 255) & ~(size_t)255;
    return p;
  };
  float* sums = (float*)alloc(16);
  float* sw   = (float*)alloc(16);
  float* rs   = (float*)alloc(4096 * 4);
  float* rs2  = (float*)alloc(4096 * 4);
  float* cosT = (float*)alloc((size_t)131072 * 4);
  float* sinT = (float*)alloc((size_t)131072 * 4);
  unsigned short* Wcat = (unsigned short*)alloc((size_t)3072 * 2048 * 2);
  unsigned short* Wot  = (unsigned short*)alloc((size_t)2048 * 2048 * 2);
  unsigned short* qb   = (unsigned short*)alloc((size_t)2 * 16 * 2048 * 128 * 2);
  unsigned short* kb   = (unsigned short*)alloc((size_t)2 * 4 * 2048 * 128 * 2);
  unsigned short* vtb  = (unsigned short*)alloc((size_t)2 * 4 * 128 * 2048 * 2);
  unsigned short* xq   = (unsigned short*)alloc((size_t)4096 * 2048 * 2);
  float* raw  = (float*)alloc((size_t)4096 * 3072 * 4);
  float* attn = raw;   // reuse: raw dead after ropeapply/transv

  hipMemsetAsync(sums, 0, 16, stream);
  absum_k<<<256, 256, 0, stream>>>(Wq, (long)2048 * 2048 / 4, sums + 0);
  absum_k<<<128, 256, 0, stream>>>(Wk, (long)512 * 2048 / 4, sums + 1);
  absum_k<<<128, 256, 0, stream>>>(Wv, (long)512 * 2048 / 4, sums + 2);
  absum_k<<<256, 256, 0, stream>>>(Wo, (long)2048 * 2048 / 4, sums + 3);
  finalize_k<<<1, 4, 0, stream>>>(sums, sw);
  quantw_k<<<512, 256, 0, stream>>>(Wq, Wcat, (long)2048 * 2048 / 4, sw + 0);
  quantw_k<<<128, 256, 0, stream>>>(Wk, Wcat + (size_t)2048 * 2048, (long)512 * 2048 / 4, sw + 1);
  quantw_k<<<128, 256, 0, stream>>>(Wv, Wcat + (size_t)2560 * 2048, (long)512 * 2048 / 4, sw + 2);
  quantw_k<<<512, 256, 0, stream>>>(Wo, Wot, (long)2048 * 2048 / 4, sw + 3);
  ropetab_k<<<512, 256, 0, stream>>>(cosT, sinT);
  quanta_k<<<4096, 256, 0, stream>>>(x, xq, rs);
  dim3 g1(3072 / 128, 4096 / 128);
  gemm_k<<<g1, 256, 0, stream>>>(xq, Wcat, raw, 4096, 3072, 2048, rs, sw, 0);
  ropeapply_k<<<4096, 256, 0, stream>>>(raw, cosT, sinT, qb, kb);
  transv_k<<<dim3(16, 4, 2), 256, 0, stream>>>(raw, vtb);
  attn_k<<<dim3(16, 16, 2), 256, 0, stream>>>(qb, kb, vtb, attn);
  quanta_k<<<4096, 256, 0, stream>>>(attn, xq, rs2);
  dim3 g2(2048 / 128, 4096 / 128);
  gemm_k<<<g2, 256, 0, stream>>>(xq, Wot, out, 4096, 2048, 2048, rs2, sw, 1);
}

// Round 4
// 378.202 us; speedup vs baseline: 2.2301x; 1.0221x over previous
//
#include <hip/hip_runtime.h>
#include <hip/hip_bf16.h>
#include <stdint.h>

typedef __bf16 bf16x8 __attribute__((ext_vector_type(8)));
typedef float f32x4 __attribute__((ext_vector_type(4)));
typedef int i32x4 __attribute__((ext_vector_type(4)));
typedef unsigned short u16x8 __attribute__((ext_vector_type(8)));
typedef unsigned short u16x4 __attribute__((ext_vector_type(4)));
typedef signed char i8x8 __attribute__((ext_vector_type(8)));
typedef signed char i8x4 __attribute__((ext_vector_type(4)));

__device__ __forceinline__ unsigned short f2bf(float f) {
  union { float f; unsigned int u; } v; v.f = f;
  unsigned int r = v.u + 0x7fffu + ((v.u >> 16) & 1u);   // RNE
  return (unsigned short)(r >> 16);
}

__device__ __forceinline__ f32x4 mfma16(bf16x8 a, bf16x8 b, f32x4 c) {
  return __builtin_amdgcn_mfma_f32_16x16x32_bf16(a, b, c, 0, 0, 0);
}

__device__ __forceinline__ i32x4 mfma_i8(i32x4 a, i32x4 b, i32x4 c) {
  return __builtin_amdgcn_mfma_i32_16x16x64_i8(a, b, c, 0, 0, 0);
}

__device__ __forceinline__ void gload_lds16(const void* g, void* l) {
  __builtin_amdgcn_global_load_lds(
      (const __attribute__((address_space(1))) void*)g,
      (__attribute__((address_space(3))) void*)l, 16, 0, 0);
}

// ---------------- abs-sum reduction (for absmean weight scale) --------------
__global__ void absum_k(const float* __restrict__ w, long n4, float* __restrict__ out) {
  long i = (long)blockIdx.x * blockDim.x + threadIdx.x;
  long stride = (long)gridDim.x * blockDim.x;
  const float4* w4 = (const float4*)w;
  float s = 0.f;
  for (; i < n4; i += stride) {
    float4 v = w4[i];
    s += fabsf(v.x) + fabsf(v.y) + fabsf(v.z) + fabsf(v.w);
  }
  #pragma unroll
  for (int o = 32; o; o >>= 1) s += __shfl_down(s, o);
  __shared__ float sm[4];
  int lane = threadIdx.x & 63, wv = threadIdx.x >> 6;
  if (lane == 0) sm[wv] = s;
  __syncthreads();
  if (threadIdx.x == 0) atomicAdd(out, sm[0] + sm[1] + sm[2] + sm[3]);
}

__global__ void finalize_k(const float* __restrict__ sums, float* __restrict__ sw) {
  int i = threadIdx.x;
  if (i < 4) {
    const float inv[4] = {1.f/(2048.f*2048.f), 1.f/(512.f*2048.f),
                          1.f/(512.f*2048.f), 1.f/(2048.f*2048.f)};
    sw[i] = sums[i] * inv[i] + 1e-5f;
  }
}

// ---------------- ternary weight quantization (store i8 {-1,0,1}) -----------
__global__ void quantw_k(const float* __restrict__ w, signed char* __restrict__ o,
                         long n4, const float* __restrict__ swp) {
  float sw = *swp;
  long i = (long)blockIdx.x * blockDim.x + threadIdx.x;
  long stride = (long)gridDim.x * blockDim.x;
  const float4* w4 = (const float4*)w;
  i8x4* o4 = (i8x4*)o;
  for (; i < n4; i += stride) {
    float4 v = w4[i];
    i8x4 t;
    t[0] = (signed char)(int)fminf(fmaxf(rintf(v.x / sw), -1.f), 1.f);
    t[1] = (signed char)(int)fminf(fmaxf(rintf(v.y / sw), -1.f), 1.f);
    t[2] = (signed char)(int)fminf(fmaxf(rintf(v.z / sw), -1.f), 1.f);
    t[3] = (signed char)(int)fminf(fmaxf(rintf(v.w / sw), -1.f), 1.f);
    o4[i] = t;
  }
}

// ---------------- RoPE tables [2048][64] ------------------------------------
__global__ void ropetab_k(float* __restrict__ cosT, float* __restrict__ sinT) {
  int idx = blockIdx.x * 256 + threadIdx.x;
  int s = idx >> 6, d = idx & 63;
  float freq = expf(-(float)d * (9.210340371976184f / 64.0f));
  float ang = (float)s * freq;
  cosT[idx] = cosf(ang);
  sinT[idx] = sinf(ang);
}

// ---------------- activation quantization (per-row absmax, i8) --------------
__global__ __launch_bounds__(256) void quanta_k(const float* __restrict__ x,
                                                signed char* __restrict__ xq,
                                                float* __restrict__ rs) {
  int row = blockIdx.x;
  const float* xr = x + (size_t)row * 2048;
  int tid = threadIdx.x;
  float4 v0 = ((const float4*)xr)[tid * 2];
  float4 v1 = ((const float4*)xr)[tid * 2 + 1];
  float m = fmaxf(fmaxf(fmaxf(fabsf(v0.x), fabsf(v0.y)), fmaxf(fabsf(v0.z), fabsf(v0.w))),
                  fmaxf(fmaxf(fabsf(v1.x), fabsf(v1.y)), fmaxf(fabsf(v1.z), fabsf(v1.w))));
  #pragma unroll
  for (int o = 32; o; o >>= 1) m = fmaxf(m, __shfl_xor(m, o));
  __shared__ float sm[4];
  if ((tid & 63) == 0) sm[tid >> 6] = m;
  __syncthreads();
  m = fmaxf(fmaxf(sm[0], sm[1]), fmaxf(sm[2], sm[3]));
  float rm = fmaxf(m, 1e-5f);
  float sx = 127.0f / rm;
  float vv[8] = {v0.x, v0.y, v0.z, v0.w, v1.x, v1.y, v1.z, v1.w};
  i8x8 o8;
  #pragma unroll
  for (int j = 0; j < 8; j++) {
    float r = rintf(vv[j] * sx);
    r = fminf(fmaxf(r, -128.f), 127.f);
    o8[j] = (signed char)(int)r;
  }
  ((i8x8*)(xq + (size_t)row * 2048))[tid] = o8;
  if (tid == 0) rs[row] = rm * (1.0f / 127.0f);
}

// ---------------- i8 GEMM (m97 structure, K-step 64, exact int math) --------
__global__ __launch_bounds__(256) void gemm_k(const signed char* __restrict__ A,
                                              const signed char* __restrict__ Bt,
                                              float* __restrict__ C,
                                              int M, int N, int K,
                                              const float* __restrict__ rowscale,
                                              const float* __restrict__ sw, int mode) {
  __shared__ alignas(16) signed char As[128 * 64];
  __shared__ alignas(16) signed char Bs[128 * 64];
  int tid = threadIdx.x;
  int lane = tid & 63, wv = tid >> 6;
  int g = lane >> 4, li = lane & 15;
  int wm = wv >> 1, wn = wv & 1;
  // XCD-aware bijective swizzle (grids are multiples of 8)
  int L = blockIdx.x + gridDim.x * blockIdx.y;
  int nwg = gridDim.x * gridDim.y;
  int swz_id = (L & 7) * (nwg >> 3) + (L >> 3);
  int m0 = (swz_id / gridDim.x) * 128, n0 = (swz_id % gridDim.x) * 128;
  int sr = lane >> 2;                      // staging row 0..15 (64B rows)
  int sc = lane & 3;                       // 16B chunk
  int gc = (sc ^ ((sr >> 1) & 3)) * 16;    // pre-swizzled global chunk (bytes)
  int swz = (g ^ ((li >> 1) & 3)) * 16;    // swizzled read chunk (bytes)
  i32x4 acc[4][4] = {};

  for (int k0 = 0; k0 < K; k0 += 64) {
    __syncthreads();
    #pragma unroll
    for (int j = 0; j < 2; j++) {
      int row = (wv * 2 + j) * 16 + sr;
      gload_lds16(&A[(size_t)(m0 + row) * K + k0 + gc], &As[(wv * 2 + j) * 1024]);
      gload_lds16(&Bt[(size_t)(n0 + row) * K + k0 + gc], &Bs[(wv * 2 + j) * 1024]);
    }
    __syncthreads();
    i32x4 af[4], bfr[4];
    #pragma unroll
    for (int i = 0; i < 4; i++)
      af[i] = *(const i32x4*)&As[(wm * 64 + i * 16 + li) * 64 + swz];
    #pragma unroll
    for (int j = 0; j < 4; j++)
      bfr[j] = *(const i32x4*)&Bs[(wn * 64 + j * 16 + li) * 64 + swz];
    #pragma unroll
    for (int i = 0; i < 4; i++)
      #pragma unroll
      for (int j = 0; j < 4; j++)
        acc[i][j] = mfma_i8(af[i], bfr[j], acc[i][j]);
  }

  #pragma unroll
  for (int i = 0; i < 4; i++) {
    int row = m0 + wm * 64 + i * 16 + g * 4;
    #pragma unroll
    for (int j = 0; j < 4; j++) {
      int col = n0 + wn * 64 + j * 16 + li;
      float s = (mode == 0) ? ((col < 2048) ? sw[0] : (col < 2560 ? sw[1] : sw[2]))
                            : sw[3];
      #pragma unroll
      for (int r = 0; r < 4; r++)
        C[(size_t)(row + r) * N + col] = (float)acc[i][j][r] * (rowscale[row + r] * s);
    }
  }
}

// ---------------- RoPE apply (Q pre-scaled by log2e/sqrt(128)) --------------
__global__ __launch_bounds__(256) void ropeapply_k(const float* __restrict__ raw,
                                                   const float* __restrict__ cosT,
                                                   const float* __restrict__ sinT,
                                                   unsigned short* __restrict__ qb,
                                                   unsigned short* __restrict__ kb) {
  const float CS = 0.1275356234f;  // log2(e)/sqrt(128)
  int r = blockIdx.x;
  int b = r >> 11, s = r & 2047;
  const float* row = raw + (size_t)r * 3072;
  int tid = threadIdx.x;
  for (int idx = tid; idx < 1024; idx += 256) {
    int h = idx >> 6, d = idx & 63;
    float x1 = row[h * 128 + d], x2 = row[h * 128 + d + 64];
    float c = cosT[s * 64 + d], sn = sinT[s * 64 + d];
    size_t base = ((size_t)(b * 16 + h) * 2048 + s) * 128;
    qb[base + d]      = f2bf((x1 * c - x2 * sn) * CS);
    qb[base + d + 64] = f2bf((x2 * c + x1 * sn) * CS);
  }
  {
    int h = tid >> 6, d = tid & 63;
    float x1 = row[2048 + h * 128 + d], x2 = row[2048 + h * 128 + d + 64];
    float c = cosT[s * 64 + d], sn = sinT[s * 64 + d];
    size_t base = ((size_t)(b * 4 + h) * 2048 + s) * 128;
    kb[base + d]      = f2bf(x1 * c - x2 * sn);
    kb[base + d + 64] = f2bf(x2 * c + x1 * sn);
  }
}

// ---------------- V transpose + PV k-permutation ----------------------------
// vtb[b][hk][d][s'] where within each 64-block, position p holds kv
// j(p) = (p>>5)*32 + ((p&7)>>2)*16 + ((p>>3)&3)*4 + (p&3)
__global__ __launch_bounds__(256) void transv_k(const float* __restrict__ raw,
                                                unsigned short* __restrict__ vtb) {
  __shared__ unsigned short T[128][136];
  int sc = blockIdx.x, hk = blockIdx.y, b = blockIdx.z;
  int tid = threadIdx.x;
  #pragma unroll
  for (int i = 0; i < 16; i++) {
    int idx4 = i * 256 + tid;
    int s = idx4 >> 5, d4 = idx4 & 31;
    float4 v = *(const float4*)&raw[((size_t)(b * 2048 + sc * 128 + s)) * 3072 +
                                    2560 + hk * 128 + d4 * 4];
    u16x4 t4;
    t4[0] = f2bf(v.x); t4[1] = f2bf(v.y); t4[2] = f2bf(v.z); t4[3] = f2bf(v.w);
    *(u16x4*)&T[s][d4 * 4] = t4;
  }
  __syncthreads();
  int d = tid >> 1, s0 = (tid & 1) * 64;
  size_t obase = ((size_t)(b * 4 + hk) * 128 + d) * 2048 + sc * 128 + s0;
  #pragma unroll
  for (int j = 0; j < 8; j++) {
    u16x8 o8;
    #pragma unroll
    for (int e = 0; e < 8; e++) {
      int kvp = (j >> 2) * 32 + (e >> 2) * 16 + (j & 3) * 4 + (e & 3);
      o8[e] = T[s0 + kvp][d];
    }
    *(u16x8*)&vtb[obase + j * 8] = o8;
  }
}

// ---------------- causal flash attention ------------------------------------
// grid (32 qtiles longest-first, 16 heads, 2 batch) x 256. Wave: 16 q rows.
// KVBLK=64. K single-buffer (prefetch between QK and PV), V double-buffer.
// P stays in registers (V pre-permuted to match the QK^T output layout).
__global__ __launch_bounds__(256) void attn_k(const unsigned short* __restrict__ qb,
                                              const unsigned short* __restrict__ kb,
                                              const unsigned short* __restrict__ vtb,
                                              float* __restrict__ out) {
  int tq = 31 - (int)blockIdx.x;   // longest blocks dispatched first
  int h = blockIdx.y, b = blockIdx.z;
  int wv = threadIdx.x >> 6, lane = threadIdx.x & 63;
  int g = lane >> 4, li = lane & 15;
  int kh = h >> 2;
  const unsigned short* qp = qb + ((size_t)(b * 16 + h) * 2048) * 128;
  const unsigned short* kp = kb + ((size_t)(b * 4 + kh) * 2048) * 128;
  const unsigned short* vp = vtb + ((size_t)(b * 4 + kh) * 128) * 2048;

  __shared__ unsigned short Ks[64 * 128];      // 16KB single buffer
  __shared__ unsigned short Vs[2][128 * 64];   // 32KB double buffer

  int qw = tq * 64 + wv * 16;
  int nt = tq + 1;
  bf16x8 qf[4];
  #pragma unroll
  for (int kk = 0; kk < 4; kk++)
    qf[kk] = *(const bf16x8*)&qp[(size_t)(qw + li) * 128 + kk * 32 + g * 8];
  f32x4 oacc[8] = {};
  float mrun = -INFINITY, lrun = 0.f;

  // ---- staging helpers (4 vm-ops per thread each) ----
  #define STAGE_K(T_) do {                                                  \
    int kv0_ = (T_) * 64;                                                   \
    _Pragma("unroll")                                                       \
    for (int i_ = 0; i_ < 4; i_++) {                                        \
      int r_ = wv * 16 + i_ * 4 + g;                                        \
      gload_lds16(kp + (size_t)(kv0_ + r_) * 128 + ((li ^ (r_ & 7)) * 8),   \
                  &Ks[(wv * 16 + i_ * 4) * 128]);                           \
    } } while (0)
  #define STAGE_V(T_, BUF_) do {                                            \
    int kv0_ = (T_) * 64;                                                   \
    _Pragma("unroll")                                                       \
    for (int i_ = 0; i_ < 4; i_++) {                                        \
      int d_ = wv * 32 + i_ * 8 + (lane >> 3);                              \
      gload_lds16(vp + (size_t)d_ * 2048 + kv0_ + (((lane & 7) ^ (d_ & 7)) * 8), \
                  &Vs[BUF_][(wv * 32 + i_ * 8) * 64]);                      \
    } } while (0)

  // prologue
  STAGE_K(0);
  STAGE_V(0, 0);
  if (nt > 1) STAGE_V(1, 1);

  #pragma unroll 1
  for (int t = 0; t < nt; ++t) {
    // A: wait K[t],V[t] landed (V[t+1] may stay in flight), sync
    if (t == nt - 1) asm volatile("s_waitcnt vmcnt(0)" ::: "memory");
    else             asm volatile("s_waitcnt vmcnt(4)" ::: "memory");
    __builtin_amdgcn_s_barrier();
    asm volatile("" ::: "memory");

    // B: QK^T swapped -> lane holds S[kv=n*16+g*4+r][q=li] (log2 domain)
    f32x4 st[4] = {};
    #pragma unroll
    for (int kk = 0; kk < 4; kk++) {
      #pragma unroll
      for (int n = 0; n < 4; n++) {
        bf16x8 kf = *(const bf16x8*)&Ks[(n * 16 + li) * 128 +
                                        (((kk * 4 + g) ^ (li & 7)) * 8)];
        st[n] = mfma16(kf, qf[kk], st[n]);
      }
    }

    // C: all waves done reading Ks -> prefetch K[t+1] into it
    asm volatile("" ::: "memory");
    __builtin_amdgcn_s_barrier();
    asm volatile("" ::: "memory");
    if (t + 1 < nt) STAGE_K(t + 1);

    // D: softmax (in-register, P stays in registers)
    if (t == nt - 1) {
      int qrel = qw + li - t * 64;
      #pragma unroll
      for (int n = 0; n < 4; n++)
        #pragma unroll
        for (int r = 0; r < 4; r++)
          if ((n * 16 + g * 4 + r) > qrel) st[n][r] = -INFINITY;
    }
    float mx = st[0][0];
    #pragma unroll
    for (int n = 0; n < 4; n++)
      #pragma unroll
      for (int r = 0; r < 4; r++) mx = fmaxf(mx, st[n][r]);
    mx = fmaxf(mx, __shfl_xor(mx, 16));
    mx = fmaxf(mx, __shfl_xor(mx, 32));
    float mnew = fmaxf(mrun, mx);
    float alpha = exp2f(mrun - mnew);
    float lsum = 0.f;
    bf16x8 pa0, pa1;
    #pragma unroll
    for (int n = 0; n < 4; n++) {
      #pragma unroll
      for (int r = 0; r < 4; r++) {
        float p = exp2f(st[n][r] - mnew);
        lsum += p;
        if (n < 2) pa0[(n & 1) * 4 + r] = (__bf16)p;
        else       pa1[(n & 1) * 4 + r] = (__bf16)p;
      }
    }
    lsum += __shfl_xor(lsum, 16);
    lsum += __shfl_xor(lsum, 32);
    lrun = lrun * alpha + lsum;
    mrun = mnew;
    if (__any(alpha != 1.0f)) {
      float ar[4];
      #pragma unroll
      for (int r = 0; r < 4; r++) ar[r] = __shfl(alpha, g * 4 + r, 64);
      #pragma unroll
      for (int dn = 0; dn < 8; dn++)
        #pragma unroll
        for (int r = 0; r < 4; r++) oacc[dn][r] *= ar[r];
    }

    // E: PV from Vs[t&1] (pre-permuted so pa0/pa1 feed directly)
    int cur = t & 1;
    #pragma unroll
    for (int dn = 0; dn < 8; dn++) {
      int d = dn * 16 + li;
      bf16x8 vf0 = *(const bf16x8*)&Vs[cur][d * 64 + ((g ^ (li & 7)) * 8)];
      bf16x8 vf1 = *(const bf16x8*)&Vs[cur][d * 64 + (((4 + g) ^ (li & 7)) * 8)];
      oacc[dn] = mfma16(pa0, vf0, oacc[dn]);
      oacc[dn] = mfma16(pa1, vf1, oacc[dn]);
    }

    // F: all waves done reading Vs[cur] -> prefetch V[t+2] into it
    asm volatile("" ::: "memory");
    __builtin_amdgcn_s_barrier();
    asm volatile("" ::: "memory");
    if (t + 2 < nt) STAGE_V(t + 2, cur);
  }
  #undef STAGE_K
  #undef STAGE_V

  float linv = 1.0f / lrun;
  float lr_[4];
  #pragma unroll
  for (int r = 0; r < 4; r++) lr_[r] = __shfl(linv, g * 4 + r, 64);
  size_t obase = ((size_t)(b * 2048 + qw + g * 4)) * 2048 + h * 128;
  #pragma unroll
  for (int dn = 0; dn < 8; dn++)
    #pragma unroll
    for (int r = 0; r < 4; r++)
      out[obase + (size_t)r * 2048 + dn * 16 + li] = oacc[dn][r] * lr_[r];
}

// ---------------------------------------------------------------------------
extern "C" void kernel_launch(void* const* d_in, const int* in_sizes, int n_in,
                              void* d_out, int out_size, void* d_ws, size_t ws_size,
                              hipStream_t stream) {
  const float* x  = (const float*)d_in[0];
  const float* Wq = (const float*)d_in[1];
  const float* Wk = (const float*)d_in[2];
  const float* Wv = (const float*)d_in[3];
  const float* Wo = (const float*)d_in[4];
  float* out = (float*)d_out;

  char* ws = (char*)d_ws;
  size_t off = 0;
  auto alloc = [&](size_t bytes) -> void* {
    void* p = ws + off;
    off = (off + bytes + 255) & ~(size_t)255;
    return p;
  };
  float* sums = (float*)alloc(16);
  float* sw   = (float*)alloc(16);
  float* rs   = (float*)alloc(4096 * 4);
  float* rs2  = (float*)alloc(4096 * 4);
  float* cosT = (float*)alloc((size_t)131072 * 4);
  float* sinT = (float*)alloc((size_t)131072 * 4);
  signed char* Wcat = (signed char*)alloc((size_t)3072 * 2048);
  signed char* Wot  = (signed char*)alloc((size_t)2048 * 2048);
  unsigned short* qb   = (unsigned short*)alloc((size_t)2 * 16 * 2048 * 128 * 2);
  unsigned short* kb   = (unsigned short*)alloc((size_t)2 * 4 * 2048 * 128 * 2);
  unsigned short* vtb  = (unsigned short*)alloc((size_t)2 * 4 * 128 * 2048 * 2);
  signed char* xq   = (signed char*)alloc((size_t)4096 * 2048);
  float* raw  = (float*)alloc((size_t)4096 * 3072 * 4);
  float* attn = raw;   // reuse: raw dead after ropeapply/transv

  hipMemsetAsync(sums, 0, 16, stream);
  absum_k<<<256, 256, 0, stream>>>(Wq, (long)2048 * 2048 / 4, sums + 0);
  absum_k<<<128, 256, 0, stream>>>(Wk, (long)512 * 2048 / 4, sums + 1);
  absum_k<<<128, 256, 0, stream>>>(Wv, (long)512 * 2048 / 4, sums + 2);
  absum_k<<<256, 256, 0, stream>>>(Wo, (long)2048 * 2048 / 4, sums + 3);
  finalize_k<<<1, 4, 0, stream>>>(sums, sw);
  quantw_k<<<512, 256, 0, stream>>>(Wq, Wcat, (long)2048 * 2048 / 4, sw + 0);
  quantw_k<<<128, 256, 0, stream>>>(Wk, Wcat + (size_t)2048 * 2048, (long)512 * 2048 / 4, sw + 1);
  quantw_k<<<128, 256, 0, stream>>>(Wv, Wcat + (size_t)2560 * 2048, (long)512 * 2048 / 4, sw + 2);
  quantw_k<<<512, 256, 0, stream>>>(Wo, Wot, (long)2048 * 2048 / 4, sw + 3);
  ropetab_k<<<512, 256, 0, stream>>>(cosT, sinT);
  quanta_k<<<4096, 256, 0, stream>>>(x, xq, rs);
  dim3 g1(3072 / 128, 4096 / 128);
  gemm_k<<<g1, 256, 0, stream>>>(xq, Wcat, raw, 4096, 3072, 2048, rs, sw, 0);
  ropeapply_k<<<4096, 256, 0, stream>>>(raw, cosT, sinT, qb, kb);
  transv_k<<<dim3(16, 4, 2), 256, 0, stream>>>(raw, vtb);
  attn_k<<<dim3(32, 16, 2), 256, 0, stream>>>(qb, kb, vtb, attn);
  quanta_k<<<4096, 256, 0, stream>>>(attn, xq, rs2);
  dim3 g2(2048 / 128, 4096 / 128);
  gemm_k<<<g2, 256, 0, stream>>>(xq, Wot, out, 4096, 2048, 2048, rs2, sw, 1);
}

// Round 6
// 323.619 us; speedup vs baseline: 2.6062x; 1.1687x over previous
//
#include <hip/hip_runtime.h>
#include <hip/hip_bf16.h>
#include <stdint.h>

typedef __bf16 bf16x8 __attribute__((ext_vector_type(8)));
typedef float f32x4 __attribute__((ext_vector_type(4)));
typedef int i32x4 __attribute__((ext_vector_type(4)));
typedef unsigned short u16x8 __attribute__((ext_vector_type(8)));
typedef unsigned short u16x4 __attribute__((ext_vector_type(4)));
typedef signed char i8x8 __attribute__((ext_vector_type(8)));
typedef signed char i8x4 __attribute__((ext_vector_type(4)));

__device__ __forceinline__ unsigned short f2bf(float f) {
  union { float f; unsigned int u; } v; v.f = f;
  unsigned int r = v.u + 0x7fffu + ((v.u >> 16) & 1u);   // RNE
  return (unsigned short)(r >> 16);
}

__device__ __forceinline__ f32x4 mfma16(bf16x8 a, bf16x8 b, f32x4 c) {
  return __builtin_amdgcn_mfma_f32_16x16x32_bf16(a, b, c, 0, 0, 0);
}

__device__ __forceinline__ i32x4 mfma_i8(i32x4 a, i32x4 b, i32x4 c) {
  return __builtin_amdgcn_mfma_i32_16x16x64_i8(a, b, c, 0, 0, 0);
}

__device__ __forceinline__ void gload_lds16(const void* g, void* l) {
  __builtin_amdgcn_global_load_lds(
      (const __attribute__((address_space(1))) void*)g,
      (__attribute__((address_space(3))) void*)l, 16, 0, 0);
}

// ---------------- abs-sum reduction (for absmean weight scale) --------------
__global__ void absum_k(const float* __restrict__ w, long n4, float* __restrict__ out) {
  long i = (long)blockIdx.x * blockDim.x + threadIdx.x;
  long stride = (long)gridDim.x * blockDim.x;
  const float4* w4 = (const float4*)w;
  float s = 0.f;
  for (; i < n4; i += stride) {
    float4 v = w4[i];
    s += fabsf(v.x) + fabsf(v.y) + fabsf(v.z) + fabsf(v.w);
  }
  #pragma unroll
  for (int o = 32; o; o >>= 1) s += __shfl_down(s, o);
  __shared__ float sm[4];
  int lane = threadIdx.x & 63, wv = threadIdx.x >> 6;
  if (lane == 0) sm[wv] = s;
  __syncthreads();
  if (threadIdx.x == 0) atomicAdd(out, sm[0] + sm[1] + sm[2] + sm[3]);
}

__global__ void finalize_k(const float* __restrict__ sums, float* __restrict__ sw) {
  int i = threadIdx.x;
  if (i < 4) {
    const float inv[4] = {1.f/(2048.f*2048.f), 1.f/(512.f*2048.f),
                          1.f/(512.f*2048.f), 1.f/(2048.f*2048.f)};
    sw[i] = sums[i] * inv[i] + 1e-5f;
  }
}

// ---------------- ternary weight quantization (store i8 {-1,0,1}) -----------
__global__ void quantw_k(const float* __restrict__ w, signed char* __restrict__ o,
                         long n4, const float* __restrict__ swp) {
  float sw = *swp;
  long i = (long)blockIdx.x * blockDim.x + threadIdx.x;
  long stride = (long)gridDim.x * blockDim.x;
  const float4* w4 = (const float4*)w;
  i8x4* o4 = (i8x4*)o;
  for (; i < n4; i += stride) {
    float4 v = w4[i];
    i8x4 t;
    t[0] = (signed char)(int)fminf(fmaxf(rintf(v.x / sw), -1.f), 1.f);
    t[1] = (signed char)(int)fminf(fmaxf(rintf(v.y / sw), -1.f), 1.f);
    t[2] = (signed char)(int)fminf(fmaxf(rintf(v.z / sw), -1.f), 1.f);
    t[3] = (signed char)(int)fminf(fmaxf(rintf(v.w / sw), -1.f), 1.f);
    o4[i] = t;
  }
}

// ---------------- RoPE tables [2048][64] ------------------------------------
__global__ void ropetab_k(float* __restrict__ cosT, float* __restrict__ sinT) {
  int idx = blockIdx.x * 256 + threadIdx.x;
  int s = idx >> 6, d = idx & 63;
  float freq = expf(-(float)d * (9.210340371976184f / 64.0f));
  float ang = (float)s * freq;
  cosT[idx] = cosf(ang);
  sinT[idx] = sinf(ang);
}

// ---------------- activation quantization (per-row absmax, i8) --------------
__global__ __launch_bounds__(256) void quanta_k(const float* __restrict__ x,
                                                signed char* __restrict__ xq,
                                                float* __restrict__ rs) {
  int row = blockIdx.x;
  const float* xr = x + (size_t)row * 2048;
  int tid = threadIdx.x;
  float4 v0 = ((const float4*)xr)[tid * 2];
  float4 v1 = ((const float4*)xr)[tid * 2 + 1];
  float m = fmaxf(fmaxf(fmaxf(fabsf(v0.x), fabsf(v0.y)), fmaxf(fabsf(v0.z), fabsf(v0.w))),
                  fmaxf(fmaxf(fabsf(v1.x), fabsf(v1.y)), fmaxf(fabsf(v1.z), fabsf(v1.w))));
  #pragma unroll
  for (int o = 32; o; o >>= 1) m = fmaxf(m, __shfl_xor(m, o));
  __shared__ float sm[4];
  if ((tid & 63) == 0) sm[tid >> 6] = m;
  __syncthreads();
  m = fmaxf(fmaxf(sm[0], sm[1]), fmaxf(sm[2], sm[3]));
  float rm = fmaxf(m, 1e-5f);
  float sx = 127.0f / rm;
  float vv[8] = {v0.x, v0.y, v0.z, v0.w, v1.x, v1.y, v1.z, v1.w};
  i8x8 o8;
  #pragma unroll
  for (int j = 0; j < 8; j++) {
    float r = rintf(vv[j] * sx);
    r = fminf(fmaxf(r, -128.f), 127.f);
    o8[j] = (signed char)(int)r;
  }
  ((i8x8*)(xq + (size_t)row * 2048))[tid] = o8;
  if (tid == 0) rs[row] = rm * (1.0f / 127.0f);
}

// ---------------- i8 GEMM (m97 structure, K-step 64, exact int math) --------
__global__ __launch_bounds__(256) void gemm_k(const signed char* __restrict__ A,
                                              const signed char* __restrict__ Bt,
                                              float* __restrict__ C,
                                              int M, int N, int K,
                                              const float* __restrict__ rowscale,
                                              const float* __restrict__ sw, int mode) {
  __shared__ alignas(16) signed char As[128 * 64];
  __shared__ alignas(16) signed char Bs[128 * 64];
  int tid = threadIdx.x;
  int lane = tid & 63, wv = tid >> 6;
  int g = lane >> 4, li = lane & 15;
  int wm = wv >> 1, wn = wv & 1;
  // XCD-aware bijective swizzle (grids are multiples of 8)
  int L = blockIdx.x + gridDim.x * blockIdx.y;
  int nwg = gridDim.x * gridDim.y;
  int swz_id = (L & 7) * (nwg >> 3) + (L >> 3);
  int m0 = (swz_id / gridDim.x) * 128, n0 = (swz_id % gridDim.x) * 128;
  int sr = lane >> 2;                      // staging row 0..15 (64B rows)
  int sc = lane & 3;                       // 16B chunk
  int gc = (sc ^ ((sr >> 1) & 3)) * 16;    // pre-swizzled global chunk (bytes)
  int swz = (g ^ ((li >> 1) & 3)) * 16;    // swizzled read chunk (bytes)
  i32x4 acc[4][4] = {};

  for (int k0 = 0; k0 < K; k0 += 64) {
    __syncthreads();
    #pragma unroll
    for (int j = 0; j < 2; j++) {
      int row = (wv * 2 + j) * 16 + sr;
      gload_lds16(&A[(size_t)(m0 + row) * K + k0 + gc], &As[(wv * 2 + j) * 1024]);
      gload_lds16(&Bt[(size_t)(n0 + row) * K + k0 + gc], &Bs[(wv * 2 + j) * 1024]);
    }
    __syncthreads();
    i32x4 af[4], bfr[4];
    #pragma unroll
    for (int i = 0; i < 4; i++)
      af[i] = *(const i32x4*)&As[(wm * 64 + i * 16 + li) * 64 + swz];
    #pragma unroll
    for (int j = 0; j < 4; j++)
      bfr[j] = *(const i32x4*)&Bs[(wn * 64 + j * 16 + li) * 64 + swz];
    #pragma unroll
    for (int i = 0; i < 4; i++)
      #pragma unroll
      for (int j = 0; j < 4; j++)
        acc[i][j] = mfma_i8(af[i], bfr[j], acc[i][j]);
  }

  #pragma unroll
  for (int i = 0; i < 4; i++) {
    int row = m0 + wm * 64 + i * 16 + g * 4;
    #pragma unroll
    for (int j = 0; j < 4; j++) {
      int col = n0 + wn * 64 + j * 16 + li;
      float s = (mode == 0) ? ((col < 2048) ? sw[0] : (col < 2560 ? sw[1] : sw[2]))
                            : sw[3];
      #pragma unroll
      for (int r = 0; r < 4; r++)
        C[(size_t)(row + r) * N + col] = (float)acc[i][j][r] * (rowscale[row + r] * s);
    }
  }
}

// ---------------- RoPE apply (Q pre-scaled by log2e/sqrt(128)) --------------
__global__ __launch_bounds__(256) void ropeapply_k(const float* __restrict__ raw,
                                                   const float* __restrict__ cosT,
                                                   const float* __restrict__ sinT,
                                                   unsigned short* __restrict__ qb,
                                                   unsigned short* __restrict__ kb) {
  const float CS = 0.1275356234f;  // log2(e)/sqrt(128)
  int r = blockIdx.x;
  int b = r >> 11, s = r & 2047;
  const float* row = raw + (size_t)r * 3072;
  int tid = threadIdx.x;
  for (int idx = tid; idx < 1024; idx += 256) {
    int h = idx >> 6, d = idx & 63;
    float x1 = row[h * 128 + d], x2 = row[h * 128 + d + 64];
    float c = cosT[s * 64 + d], sn = sinT[s * 64 + d];
    size_t base = ((size_t)(b * 16 + h) * 2048 + s) * 128;
    qb[base + d]      = f2bf((x1 * c - x2 * sn) * CS);
    qb[base + d + 64] = f2bf((x2 * c + x1 * sn) * CS);
  }
  {
    int h = tid >> 6, d = tid & 63;
    float x1 = row[2048 + h * 128 + d], x2 = row[2048 + h * 128 + d + 64];
    float c = cosT[s * 64 + d], sn = sinT[s * 64 + d];
    size_t base = ((size_t)(b * 4 + h) * 2048 + s) * 128;
    kb[base + d]      = f2bf(x1 * c - x2 * sn);
    kb[base + d + 64] = f2bf(x2 * c + x1 * sn);
  }
}

// ---------------- V transpose + PV k-permutation ----------------------------
// vtb[b][hk][d][s'] where within each 64-block, position p holds kv
// j(p) = (p>>5)*32 + ((p&7)>>2)*16 + ((p>>3)&3)*4 + (p&3)
__global__ __launch_bounds__(256) void transv_k(const float* __restrict__ raw,
                                                unsigned short* __restrict__ vtb) {
  __shared__ unsigned short T[128][136];
  int sc = blockIdx.x, hk = blockIdx.y, b = blockIdx.z;
  int tid = threadIdx.x;
  #pragma unroll
  for (int i = 0; i < 16; i++) {
    int idx4 = i * 256 + tid;
    int s = idx4 >> 5, d4 = idx4 & 31;
    float4 v = *(const float4*)&raw[((size_t)(b * 2048 + sc * 128 + s)) * 3072 +
                                    2560 + hk * 128 + d4 * 4];
    u16x4 t4;
    t4[0] = f2bf(v.x); t4[1] = f2bf(v.y); t4[2] = f2bf(v.z); t4[3] = f2bf(v.w);
    *(u16x4*)&T[s][d4 * 4] = t4;
  }
  __syncthreads();
  int d = tid >> 1, s0 = (tid & 1) * 64;
  size_t obase = ((size_t)(b * 4 + hk) * 128 + d) * 2048 + sc * 128 + s0;
  #pragma unroll
  for (int j = 0; j < 8; j++) {
    u16x8 o8;
    #pragma unroll
    for (int e = 0; e < 8; e++) {
      int kvp = (j >> 2) * 32 + (e >> 2) * 16 + (j & 3) * 4 + (e & 3);
      o8[e] = T[s0 + kvp][d];
    }
    *(u16x8*)&vtb[obase + j * 8] = o8;
  }
}

// ---------------- causal flash attention ------------------------------------
// grid 1024 x 256, GLOBAL longest-first: gid>>5 ranks q-tiles long->short so
// dispatch order matches work order (3 blocks/CU resident, minimal tail).
// Wave: 16 q rows. KVBLK=64. K single-buffer (prefetch between QK and PV),
// V double-buffer. P stays in registers (V pre-permuted to QK^T layout).
__global__ __launch_bounds__(256) void attn_k(const unsigned short* __restrict__ qb,
                                              const unsigned short* __restrict__ kb,
                                              const unsigned short* __restrict__ vtb,
                                              float* __restrict__ out) {
  int gid = blockIdx.x;
  int tq = 31 - (gid >> 5);        // all 32 (h,b) at rank r dispatch together
  int hb = gid & 31;
  int h = hb & 15, b = hb >> 4;
  int wv = threadIdx.x >> 6, lane = threadIdx.x & 63;
  int g = lane >> 4, li = lane & 15;
  int kh = h >> 2;
  const unsigned short* qp = qb + ((size_t)(b * 16 + h) * 2048) * 128;
  const unsigned short* kp = kb + ((size_t)(b * 4 + kh) * 2048) * 128;
  const unsigned short* vp = vtb + ((size_t)(b * 4 + kh) * 128) * 2048;

  __shared__ unsigned short Ks[64 * 128];      // 16KB single buffer
  __shared__ unsigned short Vs[2][128 * 64];   // 32KB double buffer

  int qw = tq * 64 + wv * 16;
  int nt = tq + 1;
  bf16x8 qf[4];
  #pragma unroll
  for (int kk = 0; kk < 4; kk++)
    qf[kk] = *(const bf16x8*)&qp[(size_t)(qw + li) * 128 + kk * 32 + g * 8];
  f32x4 oacc[8] = {};
  float mrun = -INFINITY, lrun = 0.f;

  #define STAGE_K(T_) do {                                                  \
    int kv0_ = (T_) * 64;                                                   \
    _Pragma("unroll")                                                       \
    for (int i_ = 0; i_ < 4; i_++) {                                        \
      int r_ = wv * 16 + i_ * 4 + g;                                        \
      gload_lds16(kp + (size_t)(kv0_ + r_) * 128 + ((li ^ (r_ & 7)) * 8),   \
                  &Ks[(wv * 16 + i_ * 4) * 128]);                           \
    } } while (0)
  #define STAGE_V(T_, BUF_) do {                                            \
    int kv0_ = (T_) * 64;                                                   \
    _Pragma("unroll")                                                       \
    for (int i_ = 0; i_ < 4; i_++) {                                        \
      int d_ = wv * 32 + i_ * 8 + (lane >> 3);                              \
      gload_lds16(vp + (size_t)d_ * 2048 + kv0_ + (((lane & 7) ^ (d_ & 7)) * 8), \
                  &Vs[BUF_][(wv * 32 + i_ * 8) * 64]);                      \
    } } while (0)

  // prologue
  STAGE_K(0);
  STAGE_V(0, 0);
  if (nt > 1) STAGE_V(1, 1);

  #pragma unroll 1
  for (int t = 0; t < nt; ++t) {
    // A: wait K[t],V[t] landed (deeper prefetches may stay in flight), sync
    if (t == nt - 1) asm volatile("s_waitcnt vmcnt(0)" ::: "memory");
    else             asm volatile("s_waitcnt vmcnt(4)" ::: "memory");
    __builtin_amdgcn_s_barrier();
    asm volatile("" ::: "memory");

    // B: QK^T swapped -> lane holds S[kv=n*16+g*4+r][q=li] (log2 domain)
    f32x4 st[4] = {};
    __builtin_amdgcn_s_setprio(1);
    #pragma unroll
    for (int kk = 0; kk < 4; kk++) {
      #pragma unroll
      for (int n = 0; n < 4; n++) {
        bf16x8 kf = *(const bf16x8*)&Ks[(n * 16 + li) * 128 +
                                        (((kk * 4 + g) ^ (li & 7)) * 8)];
        st[n] = mfma16(kf, qf[kk], st[n]);
      }
    }
    __builtin_amdgcn_s_setprio(0);

    // C: all waves done reading Ks -> prefetch K[t+1] into it
    asm volatile("" ::: "memory");
    __builtin_amdgcn_s_barrier();
    asm volatile("" ::: "memory");
    if (t + 1 < nt) STAGE_K(t + 1);

    // D: softmax (in-register, P stays in registers)
    if (t == nt - 1) {
      int qrel = qw + li - t * 64;
      #pragma unroll
      for (int n = 0; n < 4; n++)
        #pragma unroll
        for (int r = 0; r < 4; r++)
          if ((n * 16 + g * 4 + r) > qrel) st[n][r] = -INFINITY;
    }
    float mx = st[0][0];
    #pragma unroll
    for (int n = 0; n < 4; n++)
      #pragma unroll
      for (int r = 0; r < 4; r++) mx = fmaxf(mx, st[n][r]);
    mx = fmaxf(mx, __shfl_xor(mx, 16));
    mx = fmaxf(mx, __shfl_xor(mx, 32));
    float mnew = fmaxf(mrun, mx);
    float alpha = exp2f(mrun - mnew);
    float lsum = 0.f;
    bf16x8 pa0, pa1;
    #pragma unroll
    for (int n = 0; n < 4; n++) {
      #pragma unroll
      for (int r = 0; r < 4; r++) {
        float p = exp2f(st[n][r] - mnew);
        lsum += p;
        if (n < 2) pa0[(n & 1) * 4 + r] = (__bf16)p;
        else       pa1[(n & 1) * 4 + r] = (__bf16)p;
      }
    }
    lsum += __shfl_xor(lsum, 16);
    lsum += __shfl_xor(lsum, 32);
    lrun = lrun * alpha + lsum;
    mrun = mnew;
    if (__any(alpha != 1.0f)) {
      float ar[4];
      #pragma unroll
      for (int r = 0; r < 4; r++) ar[r] = __shfl(alpha, g * 4 + r, 64);
      #pragma unroll
      for (int dn = 0; dn < 8; dn++)
        #pragma unroll
        for (int r = 0; r < 4; r++) oacc[dn][r] *= ar[r];
    }

    // E: PV from Vs[t&1] (pre-permuted so pa0/pa1 feed directly)
    int cur = t & 1;
    __builtin_amdgcn_s_setprio(1);
    #pragma unroll
    for (int dn = 0; dn < 8; dn++) {
      int d = dn * 16 + li;
      bf16x8 vf0 = *(const bf16x8*)&Vs[cur][d * 64 + ((g ^ (li & 7)) * 8)];
      bf16x8 vf1 = *(const bf16x8*)&Vs[cur][d * 64 + (((4 + g) ^ (li & 7)) * 8)];
      oacc[dn] = mfma16(pa0, vf0, oacc[dn]);
      oacc[dn] = mfma16(pa1, vf1, oacc[dn]);
    }
    __builtin_amdgcn_s_setprio(0);

    // F: all waves done reading Vs[cur] -> prefetch V[t+2] into it
    asm volatile("" ::: "memory");
    __builtin_amdgcn_s_barrier();
    asm volatile("" ::: "memory");
    if (t + 2 < nt) STAGE_V(t + 2, cur);
  }
  #undef STAGE_K
  #undef STAGE_V

  float linv = 1.0f / lrun;
  float lr_[4];
  #pragma unroll
  for (int r = 0; r < 4; r++) lr_[r] = __shfl(linv, g * 4 + r, 64);
  size_t obase = ((size_t)(b * 2048 + qw + g * 4)) * 2048 + h * 128;
  #pragma unroll
  for (int dn = 0; dn < 8; dn++)
    #pragma unroll
    for (int r = 0; r < 4; r++)
      out[obase + (size_t)r * 2048 + dn * 16 + li] = oacc[dn][r] * lr_[r];
}

// ---------------------------------------------------------------------------
extern "C" void kernel_launch(void* const* d_in, const int* in_sizes, int n_in,
                              void* d_out, int out_size, void* d_ws, size_t ws_size,
                              hipStream_t stream) {
  const float* x  = (const float*)d_in[0];
  const float* Wq = (const float*)d_in[1];
  const float* Wk = (const float*)d_in[2];
  const float* Wv = (const float*)d_in[3];
  const float* Wo = (const float*)d_in[4];
  float* out = (float*)d_out;

  char* ws = (char*)d_ws;
  size_t off = 0;
  auto alloc = [&](size_t bytes) -> void* {
    void* p = ws + off;
    off = (off + bytes + 255) & ~(size_t)255;
    return p;
  };
  float* sums = (float*)alloc(16);
  float* sw   = (float*)alloc(16);
  float* rs   = (float*)alloc(4096 * 4);
  float* rs2  = (float*)alloc(4096 * 4);
  float* cosT = (float*)alloc((size_t)131072 * 4);
  float* sinT = (float*)alloc((size_t)131072 * 4);
  signed char* Wcat = (signed char*)alloc((size_t)3072 * 2048);
  signed char* Wot  = (signed char*)alloc((size_t)2048 * 2048);
  unsigned short* qb   = (unsigned short*)alloc((size_t)2 * 16 * 2048 * 128 * 2);
  unsigned short* kb   = (unsigned short*)alloc((size_t)2 * 4 * 2048 * 128 * 2);
  unsigned short* vtb  = (unsigned short*)alloc((size_t)2 * 4 * 128 * 2048 * 2);
  signed char* xq   = (signed char*)alloc((size_t)4096 * 2048);
  float* raw  = (float*)alloc((size_t)4096 * 3072 * 4);
  float* attn = raw;   // reuse: raw dead after ropeapply/transv

  hipMemsetAsync(sums, 0, 16, stream);
  absum_k<<<256, 256, 0, stream>>>(Wq, (long)2048 * 2048 / 4, sums + 0);
  absum_k<<<128, 256, 0, stream>>>(Wk, (long)512 * 2048 / 4, sums + 1);
  absum_k<<<128, 256, 0, stream>>>(Wv, (long)512 * 2048 / 4, sums + 2);
  absum_k<<<256, 256, 0, stream>>>(Wo, (long)2048 * 2048 / 4, sums + 3);
  finalize_k<<<1, 4, 0, stream>>>(sums, sw);
  quantw_k<<<512, 256, 0, stream>>>(Wq, Wcat, (long)2048 * 2048 / 4, sw + 0);
  quantw_k<<<128, 256, 0, stream>>>(Wk, Wcat + (size_t)2048 * 2048, (long)512 * 2048 / 4, sw + 1);
  quantw_k<<<128, 256, 0, stream>>>(Wv, Wcat + (size_t)2560 * 2048, (long)512 * 2048 / 4, sw + 2);
  quantw_k<<<512, 256, 0, stream>>>(Wo, Wot, (long)2048 * 2048 / 4, sw + 3);
  ropetab_k<<<512, 256, 0, stream>>>(cosT, sinT);
  quanta_k<<<4096, 256, 0, stream>>>(x, xq, rs);
  dim3 g1(3072 / 128, 4096 / 128);
  gemm_k<<<g1, 256, 0, stream>>>(xq, Wcat, raw, 4096, 3072, 2048, rs, sw, 0);
  ropeapply_k<<<4096, 256, 0, stream>>>(raw, cosT, sinT, qb, kb);
  transv_k<<<dim3(16, 4, 2), 256, 0, stream>>>(raw, vtb);
  attn_k<<<1024, 256, 0, stream>>>(qb, kb, vtb, attn);
  quanta_k<<<4096, 256, 0, stream>>>(attn, xq, rs2);
  dim3 g2(2048 / 128, 4096 / 128);
  gemm_k<<<g2, 256, 0, stream>>>(xq, Wot, out, 4096, 2048, 2048, rs2, sw, 1);
}